// Round 11
// baseline (5017.500 us; speedup 1.0000x reference)
//
#include <hip/hip_runtime.h>
#include <stdint.h>

typedef unsigned short u16;
typedef __attribute__((ext_vector_type(8))) short short8;
typedef __attribute__((ext_vector_type(4))) short short4v;
typedef __attribute__((ext_vector_type(4))) float f32x4;

#define DEV static __device__ __forceinline__

constexpr int B = 16, S = 256, D = 1024, H = 16, LYR = 2, FF = 4096;
constexpr int Mc = B * S;
constexpr int MAXL = 6;
constexpr int QKVS = 3 * D;

DEV u16 f2b(float f) {
  union { float f; uint32_t u; } a; a.f = f;
  uint32_t r = a.u + 0x7fffu + ((a.u >> 16) & 1u);
  return (u16)(r >> 16);
}
DEV float b2f(u16 b) {
  union { uint32_t u; float f; } a; a.u = ((uint32_t)b) << 16;
  return a.f;
}

DEV void glds16(const u16* g, u16* l) {
  __builtin_amdgcn_global_load_lds((const __attribute__((address_space(1))) void*)g,
                                   (__attribute__((address_space(3))) void*)l, 16, 0, 0);
}

// ---------------- batched weight transpose: 6 x (W[K][N] f32 -> Wt[N][K] bf16) ----------------
struct TBatch {
  const float* src[6];
  u16* dst[6];
  int Kd[6];
  int Nd[6];
  int base[6];
};

__global__ __launch_bounds__(256) void transpose_batch(TBatch tb, int unused) {
  __shared__ float tile[64][65];
  const int bid = blockIdx.x;
  int wi = 0;
#pragma unroll
  for (int i = 1; i < 6; i++)
    if (bid >= tb.base[i]) wi = i;
  const float* __restrict__ W = tb.src[wi];
  u16* __restrict__ Wt = tb.dst[wi];
  const int K = tb.Kd[wi], N = tb.Nd[wi];
  const int local = bid - tb.base[wi];
  const int ntx = N >> 6;
  const int bn = (local % ntx) * 64, bk = (local / ntx) * 64;
  const int t = threadIdx.x;
  const int lr = t >> 2, lc = (t & 3) * 16;
#pragma unroll
  for (int q = 0; q < 4; q++) {
    float4 v = *(const float4*)&W[(size_t)(bk + lr) * N + bn + lc + q * 4];
    *(float4*)&tile[lr][lc + q * 4] = v;
  }
  __syncthreads();
  const int k0 = (t & 7) * 8;
#pragma unroll
  for (int p = 0; p < 2; p++) {
    const int n = (t >> 3) + p * 32;
    short8 o;
#pragma unroll
    for (int j = 0; j < 8; j++) o[j] = (short)f2b(tile[k0 + j][n]);
    *(short8*)&Wt[(size_t)(bn + n) * K + bk + k0] = o;
  }
}

// ======== GEMM kernel 1 (R8 proven): 128x256, 4 waves, single-buffer — QKV only ========
template <int PASSES>
DEV void stage_rows(const u16* P, int lda, int k0, u16* Dst, int t) {
#pragma unroll
  for (int p = 0; p < PASSES; p++)
    glds16(P + (size_t)(p * 32) * lda + k0, Dst + p * 2048 + t * 8);
}

DEV void compute_tile(const u16* Asb, const u16* Bsb, f32x4 (&acc)[4][8],
                      int wm, int wn, int li, int hi) {
#pragma unroll
  for (int ks = 0; ks < 2; ks++) {
    const int ch = ((((ks << 2) | hi) ^ (li & 7)) * 8);
    short8 af[4], bfr[8];
#pragma unroll
    for (int i = 0; i < 4; i++)
      af[i] = *(const short8*)&Asb[(wm + i * 16 + li) * 64 + ch];
#pragma unroll
    for (int j = 0; j < 8; j++)
      bfr[j] = *(const short8*)&Bsb[(wn + j * 16 + li) * 64 + ch];
#pragma unroll
    for (int i = 0; i < 4; i++)
#pragma unroll
      for (int j = 0; j < 8; j++)
        acc[i][j] = __builtin_amdgcn_mfma_f32_16x16x32_bf16(af[i], bfr[j], acc[i][j], 0, 0, 0);
  }
}

__global__ __launch_bounds__(256, 2) void gemm_qkv(const u16* __restrict__ A,
                                                   const u16* __restrict__ Bt,
                                                   const float* __restrict__ bias0,
                                                   const float* __restrict__ bias1,
                                                   const float* __restrict__ bias2,
                                                   u16* __restrict__ Cb,
                                                   int M, int N, int K, int lda, int NB) {
  __shared__ u16 As[128 * 64];
  __shared__ u16 Bs[256 * 64];
  const int t = threadIdx.x, lane = t & 63, w = t >> 6;
  const int wm = (w >> 1) * 64, wn = (w & 1) * 128;
  const int nwg = gridDim.x;
  const int cpx = nwg >> 3;
  const int swz = (blockIdx.x & 7) * cpx + (blockIdx.x >> 3);
  const int n0 = (swz % NB) * 256, m0 = (swz / NB) * 128;
  const int pr = t >> 3;
  const int scb = (((t & 7) ^ (pr & 7)) * 8);
  f32x4 acc[4][8] = {};
  const u16* Ap = A + (size_t)(m0 + pr) * lda + scb;
  const u16* Bp = Bt + (size_t)(n0 + pr) * lda + scb;
  const int li = lane & 15, hi = lane >> 4;

  for (int k0 = 0; k0 < K; k0 += 64) {
    stage_rows<4>(Ap, lda, k0, &As[0], t);
    stage_rows<8>(Bp, lda, k0, &Bs[0], t);
    __syncthreads();
    compute_tile(&As[0], &Bs[0], acc, wm, wn, li, hi);
    __syncthreads();
  }

  const int rg = hi * 4;
#pragma unroll
  for (int j = 0; j < 8; j++) {
    const int col = n0 + wn + j * 16 + li;
    const float bv = (col < 1024 ? bias0 : col < 2048 ? bias1 : bias2)[col & 1023];
#pragma unroll
    for (int i = 0; i < 4; i++) {
      const int row0 = m0 + wm + i * 16 + rg;
#pragma unroll
      for (int r = 0; r < 4; r++)
        Cb[(size_t)(row0 + r) * N + col] = f2b(acc[i][j][r] + bv);
    }
  }
}

// ======== GEMM kernel 2: 256x256, 8 waves (512 thr), BK=64, SINGLE-buffer 2-phase ========
// R8's proven stage->sync->compute->sync at the bigger tile (m230: 256²-2ph > 128²-2ph):
// 2x FLOPs per barrier-drain event, 64KB LDS -> 2 blocks/CU (16 waves/CU TLP).
// EPI: 2 = relu->bf16+bias, 3 = bf16 partial (no bias, + sblk*M*N). SPLITK: 0 or 4.

template <int PASSES>
DEV void stage_rows2(const u16* P, int lda, int k0, u16* Dst, int t) {
#pragma unroll
  for (int p = 0; p < PASSES; p++)
    glds16(P + (size_t)(p * 64) * lda + k0, Dst + p * 4096 + t * 8);
}

DEV void compute_tile2(const u16* Asb, const u16* Bsb, f32x4 (&acc)[8][4],
                       int wm, int wn, int li, int hi) {
#pragma unroll
  for (int ks = 0; ks < 2; ks++) {
    const int ch = ((((ks << 2) | hi) ^ (li & 7)) * 8);
    short8 af[8], bfr[4];
#pragma unroll
    for (int i = 0; i < 8; i++)
      af[i] = *(const short8*)&Asb[(wm + i * 16 + li) * 64 + ch];
#pragma unroll
    for (int j = 0; j < 4; j++)
      bfr[j] = *(const short8*)&Bsb[(wn + j * 16 + li) * 64 + ch];
    __builtin_amdgcn_s_setprio(1);
#pragma unroll
    for (int i = 0; i < 8; i++)
#pragma unroll
      for (int j = 0; j < 4; j++)
        acc[i][j] = __builtin_amdgcn_mfma_f32_16x16x32_bf16(af[i], bfr[j], acc[i][j], 0, 0, 0);
    __builtin_amdgcn_s_setprio(0);
  }
}

template <int EPI, int SPLITK>
__global__ __launch_bounds__(512, 4) void gemm_bt2s(const u16* __restrict__ A,
                                                    const u16* __restrict__ Bt,
                                                    const float* __restrict__ bias0,
                                                    u16* __restrict__ Cb,
                                                    int M, int N, int K, int lda, int NB) {
  __shared__ u16 As[256 * 64];  // 32KB
  __shared__ u16 Bs[256 * 64];  // 32KB
  const int t = threadIdx.x, lane = t & 63, w = t >> 6;
  const int wm = (w >> 2) * 128, wn = (w & 3) * 64;
  const int nwg = gridDim.x;
  const int cpx = nwg >> 3;
  const int swz = ((int)blockIdx.x & 7) * cpx + ((int)blockIdx.x >> 3);
  int sblk = 0, rem = swz;
  if (SPLITK > 0) {
    const int tps = nwg / SPLITK;
    sblk = swz / tps;
    rem = swz % tps;
  }
  const int n0 = (rem % NB) * 256, m0 = (rem / NB) * 256;
  const int pr = t >> 3;
  const int scb = (((t & 7) ^ (pr & 7)) * 8);
  f32x4 acc[8][4] = {};
  const u16* Ap = A + (size_t)sblk * K + (size_t)(m0 + pr) * lda + scb;
  const u16* Bp = Bt + (size_t)sblk * K + (size_t)(n0 + pr) * lda + scb;
  const int li = lane & 15, hi = lane >> 4;

  for (int k0 = 0; k0 < K; k0 += 64) {
    stage_rows2<4>(Ap, lda, k0, &As[0], t);
    stage_rows2<4>(Bp, lda, k0, &Bs[0], t);
    __syncthreads();  // drains vmcnt; staged tile visible
    compute_tile2(&As[0], &Bs[0], acc, wm, wn, li, hi);
    __syncthreads();  // all waves done reading before next overwrite
  }

  u16* Cbs = Cb;
  if (SPLITK > 0 && EPI == 3) Cbs = Cb + (size_t)sblk * M * N;
  const int rg = hi * 4;
#pragma unroll
  for (int j = 0; j < 4; j++) {
    const int col = n0 + wn + j * 16 + li;
    float bv = 0.f;
    if (EPI != 3) bv = bias0[col];
#pragma unroll
    for (int i = 0; i < 8; i++) {
      const int row0 = m0 + wm + i * 16 + rg;
#pragma unroll
      for (int r = 0; r < 4; r++) {
        float v = acc[i][j][r] + bv;
        if (EPI == 2) v = fmaxf(v, 0.f);
        Cbs[(size_t)(row0 + r) * N + col] = f2b(v);
      }
    }
  }
}

// ---------------- per-head V transpose (from fused QKV) ----------------
__global__ __launch_bounds__(256) void transpose_v(const u16* __restrict__ QKV,
                                                   u16* __restrict__ Vt) {
  const int kb = blockIdx.x, h = blockIdx.y, b = blockIdx.z;
  __shared__ u16 tile[64][72];
  const int t = threadIdx.x, lr = t >> 3, lc = (t & 7) * 8;
#pragma unroll
  for (int p = 0; p < 2; p++) {
    int r = lr + p * 32;
    *(short8*)&tile[r][lc] =
        *(const short8*)&QKV[(size_t)(b * 256 + kb * 64 + r) * QKVS + 2048 + h * 64 + lc];
  }
  __syncthreads();
#pragma unroll
  for (int p = 0; p < 2; p++) {
    int hd = lr + p * 32;
    short8 v8;
#pragma unroll
    for (int j = 0; j < 8; j++) v8[j] = (short)tile[lc + j][hd];
    *(short8*)&Vt[(size_t)((b * 16 + h) * 64 + hd) * 256 + kb * 64 + lc] = v8;
  }
}

// ---------------- fused ctx attention ----------------
__global__ __launch_bounds__(256) void attn_ctx(const u16* __restrict__ QKV,
                                                const u16* __restrict__ Vt,
                                                u16* __restrict__ AO,
                                                const int* __restrict__ lengths) {
  const int qt = blockIdx.x, h = blockIdx.y, b = blockIdx.z;
  __shared__ u16 Qs[64 * 64], Ks[64 * 64], Vs[64 * 64], Ps[64 * 64];
  const int t = threadIdx.x, lane = t & 63, w = t >> 6;
  const int len = lengths[b];
  const bool full = (len >= 256);
  const int lr = t >> 3, lc = (t & 7) * 8;
#pragma unroll
  for (int p = 0; p < 2; p++) {
    int r = lr + p * 32;
    *(short8*)&Qs[r * 64 + lc] =
        *(const short8*)&QKV[(size_t)(b * 256 + qt * 64 + r) * QKVS + h * 64 + lc];
  }
  const int li = lane & 15, kk = (lane >> 4) * 8, rg = (lane >> 4) * 4;
  float mrun[4], lrun[4];
  f32x4 oacc[4] = {};
#pragma unroll
  for (int r = 0; r < 4; r++) { mrun[r] = -1e30f; lrun[r] = 0.f; }

  for (int kt = 0; kt < 4; kt++) {
    __syncthreads();
#pragma unroll
    for (int p = 0; p < 2; p++) {
      int r = lr + p * 32;
      *(short8*)&Ks[r * 64 + lc] =
          *(const short8*)&QKV[(size_t)(b * 256 + kt * 64 + r) * QKVS + 1024 + h * 64 + lc];
      *(short8*)&Vs[r * 64 + lc] =
          *(const short8*)&Vt[(size_t)((b * 16 + h) * 64 + r) * 256 + kt * 64 + lc];
    }
    __syncthreads();
    f32x4 s[4] = {};
    short8 aq0 = *(const short8*)&Qs[(w * 16 + li) * 64 + kk];
    short8 aq1 = *(const short8*)&Qs[(w * 16 + li) * 64 + 32 + kk];
    __builtin_amdgcn_s_setprio(1);
#pragma unroll
    for (int fn = 0; fn < 4; fn++) {
      short8 b0 = *(const short8*)&Ks[(fn * 16 + li) * 64 + kk];
      short8 b1 = *(const short8*)&Ks[(fn * 16 + li) * 64 + 32 + kk];
      s[fn] = __builtin_amdgcn_mfma_f32_16x16x32_bf16(aq0, b0, s[fn], 0, 0, 0);
      s[fn] = __builtin_amdgcn_mfma_f32_16x16x32_bf16(aq1, b1, s[fn], 0, 0, 0);
    }
    __builtin_amdgcn_s_setprio(0);
    float pv[4][4];
    if (full) {
#pragma unroll
      for (int r = 0; r < 4; r++) {
        float mx = -1e30f;
#pragma unroll
        for (int fn = 0; fn < 4; fn++) {
          float v = s[fn][r] * 0.125f;
          pv[fn][r] = v;
          mx = fmaxf(mx, v);
        }
#pragma unroll
        for (int d = 1; d < 16; d <<= 1) mx = fmaxf(mx, __shfl_xor(mx, d));
        if (mx > mrun[r] + 8.f) {
          float sf = __expf(mrun[r] - mx);
          mrun[r] = mx;
          lrun[r] *= sf;
#pragma unroll
          for (int fn = 0; fn < 4; fn++) oacc[fn][r] *= sf;
        }
        float rs = 0.f;
#pragma unroll
        for (int fn = 0; fn < 4; fn++) {
          float p = __expf(pv[fn][r] - mrun[r]);
          pv[fn][r] = p;
          rs += p;
        }
#pragma unroll
        for (int d = 1; d < 16; d <<= 1) rs += __shfl_xor(rs, d);
        lrun[r] += rs;
      }
    } else {
#pragma unroll
      for (int r = 0; r < 4; r++) {
        float mx = -1e30f;
#pragma unroll
        for (int fn = 0; fn < 4; fn++) {
          int key = kt * 64 + fn * 16 + li;
          float v = (key < len) ? s[fn][r] * 0.125f : -1e30f;
          pv[fn][r] = v;
          mx = fmaxf(mx, v);
        }
#pragma unroll
        for (int d = 1; d < 16; d <<= 1) mx = fmaxf(mx, __shfl_xor(mx, d));
        float mnew = fmaxf(mrun[r], mx);
        float sf = __expf(mrun[r] - mnew);
        mrun[r] = mnew;
        float rs = 0.f;
#pragma unroll
        for (int fn = 0; fn < 4; fn++) {
          int key = kt * 64 + fn * 16 + li;
          float p = (key < len) ? __expf(pv[fn][r] - mnew) : 0.f;
          pv[fn][r] = p;
          rs += p;
        }
#pragma unroll
        for (int d = 1; d < 16; d <<= 1) rs += __shfl_xor(rs, d);
        lrun[r] = lrun[r] * sf + rs;
#pragma unroll
        for (int fn = 0; fn < 4; fn++) oacc[fn][r] *= sf;
      }
    }
#pragma unroll
    for (int fn = 0; fn < 4; fn++)
#pragma unroll
      for (int r = 0; r < 4; r++)
        Ps[(w * 16 + rg + r) * 64 + fn * 16 + li] = f2b(pv[fn][r]);
    __builtin_amdgcn_s_setprio(1);
#pragma unroll
    for (int ks = 0; ks < 2; ks++) {
      short8 ap = *(const short8*)&Ps[(w * 16 + li) * 64 + ks * 32 + kk];
#pragma unroll
      for (int fn = 0; fn < 4; fn++) {
        short8 bv = *(const short8*)&Vs[(fn * 16 + li) * 64 + ks * 32 + kk];
        oacc[fn] = __builtin_amdgcn_mfma_f32_16x16x32_bf16(ap, bv, oacc[fn], 0, 0, 0);
      }
    }
    __builtin_amdgcn_s_setprio(0);
  }
#pragma unroll
  for (int r = 0; r < 4; r++) {
    float inv = 1.f / fmaxf(lrun[r], 1e-30f);
    int row = b * 256 + qt * 64 + w * 16 + rg + r;
#pragma unroll
    for (int fn = 0; fn < 4; fn++) {
      int col = h * 64 + fn * 16 + li;
      AO[(size_t)row * 1024 + col] = f2b(oacc[fn][r] * inv);
    }
  }
}

// ---------------- word attention ----------------
__global__ __launch_bounds__(256) void attn_word(const u16* __restrict__ QKV,
                                                 const int* __restrict__ wlen,
                                                 u16* __restrict__ AO, int NW) {
  const int idx = blockIdx.x * 256 + threadIdx.x;
  if (idx >= NW * 16 * MAXL) return;
  const int i = idx % MAXL, h = (idx / MAXL) % 16, wd = idx / (MAXL * 16);
  const int len = wlen[wd];
  const size_t rowb = (size_t)(wd * MAXL + i) * QKVS;
  float q[64];
#pragma unroll
  for (int d = 0; d < 64; d += 8) {
    short8 q8 = *(const short8*)&QKV[rowb + h * 64 + d];
#pragma unroll
    for (int e = 0; e < 8; e++) q[d + e] = b2f((u16)q8[e]);
  }
  float sc[MAXL];
  float mx = -1e30f;
  for (int j = 0; j < MAXL; j++) {
    if (j >= len) { sc[j] = -1e30f; continue; }
    const size_t koff = (size_t)(wd * MAXL + j) * QKVS + 1024 + h * 64;
    float dot = 0.f;
#pragma unroll
    for (int d = 0; d < 64; d += 8) {
      short8 k8 = *(const short8*)&QKV[koff + d];
#pragma unroll
      for (int e = 0; e < 8; e++) dot += q[d + e] * b2f((u16)k8[e]);
    }
    sc[j] = dot * 0.125f;
    mx = fmaxf(mx, sc[j]);
  }
  float p[MAXL], l = 0.f;
  for (int j = 0; j < MAXL; j++) {
    p[j] = (j < len) ? __expf(sc[j] - mx) : 0.f;
    l += p[j];
  }
  const float rl = 1.f / fmaxf(l, 1e-30f);
  for (int j = 0; j < MAXL; j++) p[j] *= rl;
#pragma unroll
  for (int d = 0; d < 64; d += 8) {
    float acc[8] = {};
    for (int j = 0; j < MAXL; j++) {
      if (j >= len) break;
      short8 v8 = *(const short8*)&QKV[(size_t)(wd * MAXL + j) * QKVS + 2048 + h * 64 + d];
#pragma unroll
      for (int e = 0; e < 8; e++) acc[e] += p[j] * b2f((u16)v8[e]);
    }
    short8 o8;
#pragma unroll
    for (int e = 0; e < 8; e++) o8[e] = (short)f2b(acc[e]);
    *(short8*)&AO[(size_t)(wd * MAXL + i) * 1024 + h * 64 + d] = o8;
  }
}

// ---------------- residual + 4 split-K bf16 partials + bias + LayerNorm ----------------
__global__ __launch_bounds__(256) void ln_resid4(const float* __restrict__ X,
                                                 const u16* __restrict__ P,
                                                 size_t pstride,
                                                 const float* __restrict__ bias,
                                                 const float* __restrict__ g,
                                                 const float* __restrict__ be,
                                                 float* __restrict__ Xo, u16* __restrict__ Xb) {
  const int row = blockIdx.x, t = threadIdx.x;
  const size_t base = (size_t)row * 1024 + t * 4;
  float4 x4 = *(const float4*)&X[base];
  float4 bb = *(const float4*)&bias[t * 4];
  float v[4] = { x4.x + bb.x, x4.y + bb.y, x4.z + bb.z, x4.w + bb.w };
#pragma unroll
  for (int k = 0; k < 4; k++) {
    short4v pk = *(const short4v*)&P[base + k * pstride];
    v[0] += b2f((u16)pk[0]);
    v[1] += b2f((u16)pk[1]);
    v[2] += b2f((u16)pk[2]);
    v[3] += b2f((u16)pk[3]);
  }
  float s = v[0] + v[1] + v[2] + v[3];
  float q = v[0] * v[0] + v[1] * v[1] + v[2] * v[2] + v[3] * v[3];
#pragma unroll
  for (int d = 1; d < 64; d <<= 1) { s += __shfl_xor(s, d); q += __shfl_xor(q, d); }
  __shared__ float ss[4], qq[4];
  if ((t & 63) == 0) { ss[t >> 6] = s; qq[t >> 6] = q; }
  __syncthreads();
  s = ss[0] + ss[1] + ss[2] + ss[3];
  q = qq[0] + qq[1] + qq[2] + qq[3];
  const float mean = s * (1.f / 1024.f);
  const float var = q * (1.f / 1024.f) - mean * mean;
  const float rstd = rsqrtf(var + 1e-5f);
  float4 gv = *(const float4*)&g[t * 4];
  float4 bv = *(const float4*)&be[t * 4];
  float y[4];
  y[0] = (v[0] - mean) * rstd * gv.x + bv.x;
  y[1] = (v[1] - mean) * rstd * gv.y + bv.y;
  y[2] = (v[2] - mean) * rstd * gv.z + bv.z;
  y[3] = (v[3] - mean) * rstd * gv.w + bv.w;
  *(float4*)&Xo[base] = make_float4(y[0], y[1], y[2], y[3]);
  short4v o = { (short)f2b(y[0]), (short)f2b(y[1]), (short)f2b(y[2]), (short)f2b(y[3]) };
  *(short4v*)&Xb[base] = o;
}

// ---------------- misc small kernels ----------------
__global__ __launch_bounds__(256) void posadd(const float* __restrict__ enc,
                                              const float* __restrict__ pos,
                                              float* __restrict__ X, u16* __restrict__ Xb) {
  const int row = blockIdx.x, t = threadIdx.x;
  const int sp = row & 255;
  const size_t base = (size_t)row * 1024 + t * 4;
  float4 e = *(const float4*)&enc[base];
  float4 p = *(const float4*)&pos[(size_t)sp * 1024 + t * 4];
  float y[4] = { e.x + p.x, e.y + p.y, e.z + p.z, e.w + p.w };
  *(float4*)&X[base] = make_float4(y[0], y[1], y[2], y[3]);
  short4v o = { (short)f2b(y[0]), (short)f2b(y[1]), (short)f2b(y[2]), (short)f2b(y[3]) };
  *(short4v*)&Xb[base] = o;
}

__global__ void scan_words(const int* __restrict__ labels, int* __restrict__ t2w,
                           int* __restrict__ t2s, int* __restrict__ wlen) {
  __shared__ int rowEnds[16], rowBase[16];
  const int t = threadIdx.x;
  if (t < 16) {
    int c = 0;
    for (int s = 0; s < 256; s++) c += (labels[t * 256 + s] == 2);
    rowEnds[t] = c;
  }
  __syncthreads();
  if (t == 0) {
    int acc = 0;
    for (int b2 = 0; b2 < 16; b2++) { rowBase[b2] = acc; acc += rowEnds[b2]; }
  }
  __syncthreads();
  if (t < 16) {
    int wc = rowBase[t], fr = 0;
    for (int s = 0; s < 256; s++) {
      const int tok = t * 256 + s, lb = labels[tok];
      if (lb == 1) { fr++; t2w[tok] = wc; t2s[tok] = fr; }
      else if (lb == 2) { t2w[tok] = wc; t2s[tok] = fr + 1; wlen[wc] = fr + 3; wc++; fr = 0; }
      else { t2w[tok] = -1; t2s[tok] = 0; fr = 0; }
    }
  }
}

// build_winp now also writes the bf16 mirror (rows later hit by scatter get overwritten there)
__global__ __launch_bounds__(256) void build_winp(const float* __restrict__ pos,
                                                  const float* __restrict__ spec,
                                                  const int* __restrict__ wlen,
                                                  float* __restrict__ XW,
                                                  u16* __restrict__ Xb) {
  const int row = blockIdx.x;
  const int wd = row / MAXL, sl = row % MAXL;
  const int len = wlen[wd];
  const int t = threadIdx.x;
  const size_t cb = t * 4;
  float4 p = *(const float4*)&pos[(size_t)sl * 1024 + cb];
  float4 e = make_float4(0.f, 0.f, 0.f, 0.f);
  if (sl == 0) e = *(const float4*)&spec[cb];
  else if (sl == len - 1) e = *(const float4*)&spec[1024 + cb];
  float y[4] = { p.x + e.x, p.y + e.y, p.z + e.z, p.w + e.w };
  *(float4*)&XW[(size_t)row * 1024 + cb] = make_float4(y[0], y[1], y[2], y[3]);
  short4v o = { (short)f2b(y[0]), (short)f2b(y[1]), (short)f2b(y[2]), (short)f2b(y[3]) };
  *(short4v*)&Xb[(size_t)row * 1024 + cb] = o;
}

// scatter_tokens writes final f32 + bf16 for the rows it touches
__global__ __launch_bounds__(256) void scatter_tokens(const float* __restrict__ Xc,
                                                      const int* __restrict__ t2w,
                                                      const int* __restrict__ t2s,
                                                      float* __restrict__ XW,
                                                      u16* __restrict__ Xb) {
  const int tok = blockIdx.x;
  const int wd = t2w[tok];
  if (wd < 0) return;
  const int row = wd * MAXL + t2s[tok];
  const size_t cb = threadIdx.x * 4;
  float4 a = *(const float4*)&Xc[(size_t)tok * 1024 + cb];
  float* dst = &XW[(size_t)row * 1024 + cb];
  float4 b2 = *(const float4*)dst;
  float y[4] = { a.x + b2.x, a.y + b2.y, a.z + b2.z, a.w + b2.w };
  *(float4*)dst = make_float4(y[0], y[1], y[2], y[3]);
  short4v o = { (short)f2b(y[0]), (short)f2b(y[1]), (short)f2b(y[2]), (short)f2b(y[3]) };
  *(short4v*)&Xb[(size_t)row * 1024 + cb] = o;
}

__global__ __launch_bounds__(256) void gather_out(const float* __restrict__ XW,
                                                  float* __restrict__ out) {
  const int wd = blockIdx.x;
  const size_t cb = threadIdx.x * 4;
  *(float4*)&out[(size_t)wd * 1024 + cb] =
      *(const float4*)&XW[(size_t)(wd * MAXL) * 1024 + cb];
}

// ---------------- host side ----------------
extern "C" void kernel_launch(void* const* d_in, const int* in_sizes, int n_in,
                              void* d_out, int out_size, void* d_ws, size_t ws_size,
                              hipStream_t stream) {
  const float* encoded = (const float*)d_in[0];
  const int* lengths = (const int*)d_in[1];
  const int* labels = (const int*)d_in[2];
  const float* pos = (const float*)d_in[4];
  const float* spec = (const float*)d_in[5];
  const float* W[2][16];
  for (int p = 0; p < 2; p++)
    for (int i = 0; i < 16; i++) W[p][i] = (const float*)d_in[6 + p * 16 + i];

  const int NW = out_size / D;  // 1024 words
  const int Mw = NW * MAXL;     // 6144 word-slot rows

  char* wp = (char*)d_ws;
  size_t off = 0;
  auto alloc = [&](size_t bytes) {
    void* r = wp + off;
    off += (bytes + 255) & ~(size_t)255;
    return r;
  };
  float* x_ctx = (float*)alloc((size_t)Mc * D * 4);
  float* x_word = (float*)alloc((size_t)Mw * D * 4);
  u16* xb = (u16*)alloc((size_t)Mw * D * 2);
  u16* wtQKV = (u16*)alloc((size_t)3 * D * D * 2);
  u16* wtO = (u16*)alloc((size_t)D * D * 2);
  u16* wtW1 = (u16*)alloc((size_t)D * FF * 2);
  u16* wtW2 = (u16*)alloc((size_t)D * FF * 2);
  char* uni = (char*)alloc((size_t)Mw * FF * 2);  // QKV(36MB)+Vt(8MB) | hb(48MB)
  u16* QKV = (u16*)uni;
  u16* Vt = (u16*)(uni + ((size_t)40 << 20));
  u16* hb = (u16*)uni;
  u16* AOb = (u16*)alloc((size_t)Mw * D * 2);
  u16* tmpb = (u16*)alloc((size_t)4 * Mw * D * 2);  // 4 split-K bf16 partials
  int* t2w = (int*)alloc((size_t)Mc * 4);
  int* t2s = (int*)alloc((size_t)Mc * 4);
  int* wlen = (int*)alloc((size_t)NW * 4);
  (void)ws_size; (void)in_sizes; (void)n_in;

  posadd<<<Mc, 256, 0, stream>>>(encoded, pos, x_ctx, xb);

  auto run_encoder = [&](int p, float* X, int M, bool is_ctx) {
    for (int l = 0; l < LYR; l++) {
      const size_t oDD = (size_t)l * D * D, oDF = (size_t)l * D * FF;
      TBatch tb;
      tb.src[0] = W[p][0] + oDD; tb.dst[0] = wtQKV;               tb.Kd[0] = D;  tb.Nd[0] = D;
      tb.src[1] = W[p][1] + oDD; tb.dst[1] = wtQKV + (size_t)D * D;   tb.Kd[1] = D;  tb.Nd[1] = D;
      tb.src[2] = W[p][2] + oDD; tb.dst[2] = wtQKV + (size_t)2 * D * D; tb.Kd[2] = D; tb.Nd[2] = D;
      tb.src[3] = W[p][3] + oDD; tb.dst[3] = wtO;                 tb.Kd[3] = D;  tb.Nd[3] = D;
      tb.src[4] = W[p][11] + oDF; tb.dst[4] = wtW1;               tb.Kd[4] = D;  tb.Nd[4] = FF;
      tb.src[5] = W[p][13] + oDF; tb.dst[5] = wtW2;               tb.Kd[5] = FF; tb.Nd[5] = D;
      int base = 0;
      for (int i = 0; i < 6; i++) {
        tb.base[i] = base;
        base += (tb.Kd[i] / 64) * (tb.Nd[i] / 64);
      }
      transpose_batch<<<base, 256, 0, stream>>>(tb, 0);

      // fused QKV projection (128x256 kernel; grids 384/576)
      gemm_qkv<<<(3 * D / 256) * (M / 128), 256, 0, stream>>>(
          xb, wtQKV, W[p][4] + (size_t)l * D, W[p][5] + (size_t)l * D,
          W[p][6] + (size_t)l * D, QKV, M, 3 * D, D, D, 3 * D / 256);
      if (is_ctx) {
        transpose_v<<<dim3(4, H, B), 256, 0, stream>>>(QKV, Vt);
        attn_ctx<<<dim3(4, H, B), 256, 0, stream>>>(QKV, Vt, AOb, lengths);
      } else {
        attn_word<<<(NW * H * MAXL + 255) / 256, 256, 0, stream>>>(QKV, wlen, AOb, NW);
      }
      // O projection: 256² single-buffer, splitK=4 (grids 256/384)
      gemm_bt2s<3, 4><<<4 * (D / 256) * (M / 256), 512, 0, stream>>>(
          AOb, wtO, nullptr, tmpb, M, D, 256, D, D / 256);
      ln_resid4<<<M, 256, 0, stream>>>(X, tmpb, (size_t)M * D, W[p][7] + (size_t)l * D,
                                       W[p][14] + (size_t)l * D, W[p][9] + (size_t)l * D, X, xb);
      // FFN1: 256² single-buffer (bias+relu in-GEMM; grids 256/384)
      gemm_bt2s<2, 0><<<(FF / 256) * (M / 256), 512, 0, stream>>>(
          xb, wtW1, W[p][12] + (size_t)l * FF, hb, M, FF, D, D, FF / 256);
      // FFN2: 256² single-buffer, splitK=4
      gemm_bt2s<3, 4><<<4 * (D / 256) * (M / 256), 512, 0, stream>>>(
          hb, wtW2, nullptr, tmpb, M, D, 1024, FF, D / 256);
      ln_resid4<<<M, 256, 0, stream>>>(X, tmpb, (size_t)M * D, W[p][8] + (size_t)l * D,
                                       W[p][15] + (size_t)l * D, W[p][10] + (size_t)l * D, X, xb);
    }
  };

  run_encoder(0, x_ctx, Mc, true);

  scan_words<<<1, 64, 0, stream>>>(labels, t2w, t2s, wlen);
  build_winp<<<Mw, 256, 0, stream>>>(pos, spec, wlen, x_word, xb);
  scatter_tokens<<<Mc, 256, 0, stream>>>(x_ctx, t2w, t2s, x_word, xb);

  run_encoder(1, x_word, Mw, false);

  gather_out<<<NW, 256, 0, stream>>>(x_word, (float*)d_out);
}

// Round 12
// 1184.011 us; speedup vs baseline: 4.2377x; 4.2377x over previous
//
#include <hip/hip_runtime.h>
#include <stdint.h>

typedef unsigned short u16;
typedef __attribute__((ext_vector_type(8))) short short8;
typedef __attribute__((ext_vector_type(4))) short short4v;
typedef __attribute__((ext_vector_type(4))) float f32x4;

#define DEV static __device__ __forceinline__

constexpr int B = 16, S = 256, D = 1024, H = 16, LYR = 2, FF = 4096;
constexpr int Mc = B * S;
constexpr int MAXL = 6;
constexpr int QKVS = 3 * D;

DEV u16 f2b(float f) {
  union { float f; uint32_t u; } a; a.f = f;
  uint32_t r = a.u + 0x7fffu + ((a.u >> 16) & 1u);
  return (u16)(r >> 16);
}
DEV float b2f(u16 b) {
  union { uint32_t u; float f; } a; a.u = ((uint32_t)b) << 16;
  return a.f;
}

DEV void glds16(const u16* g, u16* l) {
  __builtin_amdgcn_global_load_lds((const __attribute__((address_space(1))) void*)g,
                                   (__attribute__((address_space(3))) void*)l, 16, 0, 0);
}

// ---------------- batched weight transpose: 6 x (W[K][N] f32 -> Wt[N][K] bf16) ----------------
struct TBatch {
  const float* src[6];
  u16* dst[6];
  int Kd[6];
  int Nd[6];
  int base[6];
};

__global__ __launch_bounds__(256) void transpose_batch(TBatch tb, int unused) {
  __shared__ float tile[64][65];
  const int bid = blockIdx.x;
  int wi = 0;
#pragma unroll
  for (int i = 1; i < 6; i++)
    if (bid >= tb.base[i]) wi = i;
  const float* __restrict__ W = tb.src[wi];
  u16* __restrict__ Wt = tb.dst[wi];
  const int K = tb.Kd[wi], N = tb.Nd[wi];
  const int local = bid - tb.base[wi];
  const int ntx = N >> 6;
  const int bn = (local % ntx) * 64, bk = (local / ntx) * 64;
  const int t = threadIdx.x;
  const int lr = t >> 2, lc = (t & 3) * 16;
#pragma unroll
  for (int q = 0; q < 4; q++) {
    float4 v = *(const float4*)&W[(size_t)(bk + lr) * N + bn + lc + q * 4];
    *(float4*)&tile[lr][lc + q * 4] = v;
  }
  __syncthreads();
  const int k0 = (t & 7) * 8;
#pragma unroll
  for (int p = 0; p < 2; p++) {
    const int n = (t >> 3) + p * 32;
    short8 o;
#pragma unroll
    for (int j = 0; j < 8; j++) o[j] = (short)f2b(tile[k0 + j][n]);
    *(short8*)&Wt[(size_t)(bn + n) * K + bk + k0] = o;
  }
}

// ======== GEMM kernel 1 (R8 proven): 128x256, 4 waves, single-buffer — QKV only ========
template <int PASSES>
DEV void stage_rows(const u16* P, int lda, int k0, u16* Dst, int t) {
#pragma unroll
  for (int p = 0; p < PASSES; p++)
    glds16(P + (size_t)(p * 32) * lda + k0, Dst + p * 2048 + t * 8);
}

DEV void compute_tile(const u16* Asb, const u16* Bsb, f32x4 (&acc)[4][8],
                      int wm, int wn, int li, int hi) {
#pragma unroll
  for (int ks = 0; ks < 2; ks++) {
    const int ch = ((((ks << 2) | hi) ^ (li & 7)) * 8);
    short8 af[4], bfr[8];
#pragma unroll
    for (int i = 0; i < 4; i++)
      af[i] = *(const short8*)&Asb[(wm + i * 16 + li) * 64 + ch];
#pragma unroll
    for (int j = 0; j < 8; j++)
      bfr[j] = *(const short8*)&Bsb[(wn + j * 16 + li) * 64 + ch];
#pragma unroll
    for (int i = 0; i < 4; i++)
#pragma unroll
      for (int j = 0; j < 8; j++)
        acc[i][j] = __builtin_amdgcn_mfma_f32_16x16x32_bf16(af[i], bfr[j], acc[i][j], 0, 0, 0);
  }
}

__global__ __launch_bounds__(256, 2) void gemm_qkv(const u16* __restrict__ A,
                                                   const u16* __restrict__ Bt,
                                                   const float* __restrict__ bias0,
                                                   const float* __restrict__ bias1,
                                                   const float* __restrict__ bias2,
                                                   u16* __restrict__ Cb,
                                                   int M, int N, int K, int lda, int NB) {
  __shared__ u16 As[128 * 64];
  __shared__ u16 Bs[256 * 64];
  const int t = threadIdx.x, lane = t & 63, w = t >> 6;
  const int wm = (w >> 1) * 64, wn = (w & 1) * 128;
  const int nwg = gridDim.x;
  const int cpx = nwg >> 3;
  const int swz = (blockIdx.x & 7) * cpx + (blockIdx.x >> 3);
  const int n0 = (swz % NB) * 256, m0 = (swz / NB) * 128;
  const int pr = t >> 3;
  const int scb = (((t & 7) ^ (pr & 7)) * 8);
  f32x4 acc[4][8] = {};
  const u16* Ap = A + (size_t)(m0 + pr) * lda + scb;
  const u16* Bp = Bt + (size_t)(n0 + pr) * lda + scb;
  const int li = lane & 15, hi = lane >> 4;

  for (int k0 = 0; k0 < K; k0 += 64) {
    stage_rows<4>(Ap, lda, k0, &As[0], t);
    stage_rows<8>(Bp, lda, k0, &Bs[0], t);
    __syncthreads();
    compute_tile(&As[0], &Bs[0], acc, wm, wn, li, hi);
    __syncthreads();
  }

  const int rg = hi * 4;
#pragma unroll
  for (int j = 0; j < 8; j++) {
    const int col = n0 + wn + j * 16 + li;
    const float bv = (col < 1024 ? bias0 : col < 2048 ? bias1 : bias2)[col & 1023];
#pragma unroll
    for (int i = 0; i < 4; i++) {
      const int row0 = m0 + wm + i * 16 + rg;
#pragma unroll
      for (int r = 0; r < 4; r++)
        Cb[(size_t)(row0 + r) * N + col] = f2b(acc[i][j][r] + bv);
    }
  }
}

// ======== GEMM kernel 2: 256x256, 8 waves (512 thr), BK=64, SINGLE-buffer 2-phase ========
// __launch_bounds__(512, 1): R9-measured 124 VGPR, no spill -> natural 2 blocks/CU.
// (R10's (512,4) capped VGPRs below the 128-reg accumulator -> scratch spill, 5x slowdown.)
// EPI: 2 = relu->bf16+bias, 3 = bf16 partial (no bias, + sblk*M*N). SPLITK: 0 or 4.

template <int PASSES>
DEV void stage_rows2(const u16* P, int lda, int k0, u16* Dst, int t) {
#pragma unroll
  for (int p = 0; p < PASSES; p++)
    glds16(P + (size_t)(p * 64) * lda + k0, Dst + p * 4096 + t * 8);
}

DEV void compute_tile2(const u16* Asb, const u16* Bsb, f32x4 (&acc)[8][4],
                       int wm, int wn, int li, int hi) {
#pragma unroll
  for (int ks = 0; ks < 2; ks++) {
    const int ch = ((((ks << 2) | hi) ^ (li & 7)) * 8);
    short8 af[8], bfr[4];
#pragma unroll
    for (int i = 0; i < 8; i++)
      af[i] = *(const short8*)&Asb[(wm + i * 16 + li) * 64 + ch];
#pragma unroll
    for (int j = 0; j < 4; j++)
      bfr[j] = *(const short8*)&Bsb[(wn + j * 16 + li) * 64 + ch];
    __builtin_amdgcn_s_setprio(1);
#pragma unroll
    for (int i = 0; i < 8; i++)
#pragma unroll
      for (int j = 0; j < 4; j++)
        acc[i][j] = __builtin_amdgcn_mfma_f32_16x16x32_bf16(af[i], bfr[j], acc[i][j], 0, 0, 0);
    __builtin_amdgcn_s_setprio(0);
  }
}

template <int EPI, int SPLITK>
__global__ __launch_bounds__(512, 1) void gemm_bt2s(const u16* __restrict__ A,
                                                    const u16* __restrict__ Bt,
                                                    const float* __restrict__ bias0,
                                                    u16* __restrict__ Cb,
                                                    int M, int N, int K, int lda, int NB) {
  __shared__ u16 As[256 * 64];  // 32KB
  __shared__ u16 Bs[256 * 64];  // 32KB
  const int t = threadIdx.x, lane = t & 63, w = t >> 6;
  const int wm = (w >> 2) * 128, wn = (w & 3) * 64;
  const int nwg = gridDim.x;
  const int cpx = nwg >> 3;
  const int swz = ((int)blockIdx.x & 7) * cpx + ((int)blockIdx.x >> 3);
  int sblk = 0, rem = swz;
  if (SPLITK > 0) {
    const int tps = nwg / SPLITK;
    sblk = swz / tps;
    rem = swz % tps;
  }
  const int n0 = (rem % NB) * 256, m0 = (rem / NB) * 256;
  const int pr = t >> 3;
  const int scb = (((t & 7) ^ (pr & 7)) * 8);
  f32x4 acc[8][4] = {};
  const u16* Ap = A + (size_t)sblk * K + (size_t)(m0 + pr) * lda + scb;
  const u16* Bp = Bt + (size_t)sblk * K + (size_t)(n0 + pr) * lda + scb;
  const int li = lane & 15, hi = lane >> 4;

  for (int k0 = 0; k0 < K; k0 += 64) {
    stage_rows2<4>(Ap, lda, k0, &As[0], t);
    stage_rows2<4>(Bp, lda, k0, &Bs[0], t);
    __syncthreads();  // drains vmcnt; staged tile visible
    compute_tile2(&As[0], &Bs[0], acc, wm, wn, li, hi);
    __syncthreads();  // all waves done reading before next overwrite
  }

  u16* Cbs = Cb;
  if (SPLITK > 0 && EPI == 3) Cbs = Cb + (size_t)sblk * M * N;
  const int rg = hi * 4;
#pragma unroll
  for (int j = 0; j < 4; j++) {
    const int col = n0 + wn + j * 16 + li;
    float bv = 0.f;
    if (EPI != 3) bv = bias0[col];
#pragma unroll
    for (int i = 0; i < 8; i++) {
      const int row0 = m0 + wm + i * 16 + rg;
#pragma unroll
      for (int r = 0; r < 4; r++) {
        float v = acc[i][j][r] + bv;
        if (EPI == 2) v = fmaxf(v, 0.f);
        Cbs[(size_t)(row0 + r) * N + col] = f2b(v);
      }
    }
  }
}

// ---------------- per-head V transpose (from fused QKV) ----------------
__global__ __launch_bounds__(256) void transpose_v(const u16* __restrict__ QKV,
                                                   u16* __restrict__ Vt) {
  const int kb = blockIdx.x, h = blockIdx.y, b = blockIdx.z;
  __shared__ u16 tile[64][72];
  const int t = threadIdx.x, lr = t >> 3, lc = (t & 7) * 8;
#pragma unroll
  for (int p = 0; p < 2; p++) {
    int r = lr + p * 32;
    *(short8*)&tile[r][lc] =
        *(const short8*)&QKV[(size_t)(b * 256 + kb * 64 + r) * QKVS + 2048 + h * 64 + lc];
  }
  __syncthreads();
#pragma unroll
  for (int p = 0; p < 2; p++) {
    int hd = lr + p * 32;
    short8 v8;
#pragma unroll
    for (int j = 0; j < 8; j++) v8[j] = (short)tile[lc + j][hd];
    *(short8*)&Vt[(size_t)((b * 16 + h) * 64 + hd) * 256 + kb * 64 + lc] = v8;
  }
}

// ---------------- fused ctx attention ----------------
__global__ __launch_bounds__(256) void attn_ctx(const u16* __restrict__ QKV,
                                                const u16* __restrict__ Vt,
                                                u16* __restrict__ AO,
                                                const int* __restrict__ lengths) {
  const int qt = blockIdx.x, h = blockIdx.y, b = blockIdx.z;
  __shared__ u16 Qs[64 * 64], Ks[64 * 64], Vs[64 * 64], Ps[64 * 64];
  const int t = threadIdx.x, lane = t & 63, w = t >> 6;
  const int len = lengths[b];
  const bool full = (len >= 256);
  const int lr = t >> 3, lc = (t & 7) * 8;
#pragma unroll
  for (int p = 0; p < 2; p++) {
    int r = lr + p * 32;
    *(short8*)&Qs[r * 64 + lc] =
        *(const short8*)&QKV[(size_t)(b * 256 + qt * 64 + r) * QKVS + h * 64 + lc];
  }
  const int li = lane & 15, kk = (lane >> 4) * 8, rg = (lane >> 4) * 4;
  float mrun[4], lrun[4];
  f32x4 oacc[4] = {};
#pragma unroll
  for (int r = 0; r < 4; r++) { mrun[r] = -1e30f; lrun[r] = 0.f; }

  for (int kt = 0; kt < 4; kt++) {
    __syncthreads();
#pragma unroll
    for (int p = 0; p < 2; p++) {
      int r = lr + p * 32;
      *(short8*)&Ks[r * 64 + lc] =
          *(const short8*)&QKV[(size_t)(b * 256 + kt * 64 + r) * QKVS + 1024 + h * 64 + lc];
      *(short8*)&Vs[r * 64 + lc] =
          *(const short8*)&Vt[(size_t)((b * 16 + h) * 64 + r) * 256 + kt * 64 + lc];
    }
    __syncthreads();
    f32x4 s[4] = {};
    short8 aq0 = *(const short8*)&Qs[(w * 16 + li) * 64 + kk];
    short8 aq1 = *(const short8*)&Qs[(w * 16 + li) * 64 + 32 + kk];
    __builtin_amdgcn_s_setprio(1);
#pragma unroll
    for (int fn = 0; fn < 4; fn++) {
      short8 b0 = *(const short8*)&Ks[(fn * 16 + li) * 64 + kk];
      short8 b1 = *(const short8*)&Ks[(fn * 16 + li) * 64 + 32 + kk];
      s[fn] = __builtin_amdgcn_mfma_f32_16x16x32_bf16(aq0, b0, s[fn], 0, 0, 0);
      s[fn] = __builtin_amdgcn_mfma_f32_16x16x32_bf16(aq1, b1, s[fn], 0, 0, 0);
    }
    __builtin_amdgcn_s_setprio(0);
    float pv[4][4];
    if (full) {
#pragma unroll
      for (int r = 0; r < 4; r++) {
        float mx = -1e30f;
#pragma unroll
        for (int fn = 0; fn < 4; fn++) {
          float v = s[fn][r] * 0.125f;
          pv[fn][r] = v;
          mx = fmaxf(mx, v);
        }
#pragma unroll
        for (int d = 1; d < 16; d <<= 1) mx = fmaxf(mx, __shfl_xor(mx, d));
        if (mx > mrun[r] + 8.f) {
          float sf = __expf(mrun[r] - mx);
          mrun[r] = mx;
          lrun[r] *= sf;
#pragma unroll
          for (int fn = 0; fn < 4; fn++) oacc[fn][r] *= sf;
        }
        float rs = 0.f;
#pragma unroll
        for (int fn = 0; fn < 4; fn++) {
          float p = __expf(pv[fn][r] - mrun[r]);
          pv[fn][r] = p;
          rs += p;
        }
#pragma unroll
        for (int d = 1; d < 16; d <<= 1) rs += __shfl_xor(rs, d);
        lrun[r] += rs;
      }
    } else {
#pragma unroll
      for (int r = 0; r < 4; r++) {
        float mx = -1e30f;
#pragma unroll
        for (int fn = 0; fn < 4; fn++) {
          int key = kt * 64 + fn * 16 + li;
          float v = (key < len) ? s[fn][r] * 0.125f : -1e30f;
          pv[fn][r] = v;
          mx = fmaxf(mx, v);
        }
#pragma unroll
        for (int d = 1; d < 16; d <<= 1) mx = fmaxf(mx, __shfl_xor(mx, d));
        float mnew = fmaxf(mrun[r], mx);
        float sf = __expf(mrun[r] - mnew);
        mrun[r] = mnew;
        float rs = 0.f;
#pragma unroll
        for (int fn = 0; fn < 4; fn++) {
          int key = kt * 64 + fn * 16 + li;
          float p = (key < len) ? __expf(pv[fn][r] - mnew) : 0.f;
          pv[fn][r] = p;
          rs += p;
        }
#pragma unroll
        for (int d = 1; d < 16; d <<= 1) rs += __shfl_xor(rs, d);
        lrun[r] = lrun[r] * sf + rs;
#pragma unroll
        for (int fn = 0; fn < 4; fn++) oacc[fn][r] *= sf;
      }
    }
#pragma unroll
    for (int fn = 0; fn < 4; fn++)
#pragma unroll
      for (int r = 0; r < 4; r++)
        Ps[(w * 16 + rg + r) * 64 + fn * 16 + li] = f2b(pv[fn][r]);
    __builtin_amdgcn_s_setprio(1);
#pragma unroll
    for (int ks = 0; ks < 2; ks++) {
      short8 ap = *(const short8*)&Ps[(w * 16 + li) * 64 + ks * 32 + kk];
#pragma unroll
      for (int fn = 0; fn < 4; fn++) {
        short8 bv = *(const short8*)&Vs[(fn * 16 + li) * 64 + ks * 32 + kk];
        oacc[fn] = __builtin_amdgcn_mfma_f32_16x16x32_bf16(ap, bv, oacc[fn], 0, 0, 0);
      }
    }
    __builtin_amdgcn_s_setprio(0);
  }
#pragma unroll
  for (int r = 0; r < 4; r++) {
    float inv = 1.f / fmaxf(lrun[r], 1e-30f);
    int row = b * 256 + qt * 64 + w * 16 + rg + r;
#pragma unroll
    for (int fn = 0; fn < 4; fn++) {
      int col = h * 64 + fn * 16 + li;
      AO[(size_t)row * 1024 + col] = f2b(oacc[fn][r] * inv);
    }
  }
}

// ---------------- word attention ----------------
__global__ __launch_bounds__(256) void attn_word(const u16* __restrict__ QKV,
                                                 const int* __restrict__ wlen,
                                                 u16* __restrict__ AO, int NW) {
  const int idx = blockIdx.x * 256 + threadIdx.x;
  if (idx >= NW * 16 * MAXL) return;
  const int i = idx % MAXL, h = (idx / MAXL) % 16, wd = idx / (MAXL * 16);
  const int len = wlen[wd];
  const size_t rowb = (size_t)(wd * MAXL + i) * QKVS;
  float q[64];
#pragma unroll
  for (int d = 0; d < 64; d += 8) {
    short8 q8 = *(const short8*)&QKV[rowb + h * 64 + d];
#pragma unroll
    for (int e = 0; e < 8; e++) q[d + e] = b2f((u16)q8[e]);
  }
  float sc[MAXL];
  float mx = -1e30f;
  for (int j = 0; j < MAXL; j++) {
    if (j >= len) { sc[j] = -1e30f; continue; }
    const size_t koff = (size_t)(wd * MAXL + j) * QKVS + 1024 + h * 64;
    float dot = 0.f;
#pragma unroll
    for (int d = 0; d < 64; d += 8) {
      short8 k8 = *(const short8*)&QKV[koff + d];
#pragma unroll
      for (int e = 0; e < 8; e++) dot += q[d + e] * b2f((u16)k8[e]);
    }
    sc[j] = dot * 0.125f;
    mx = fmaxf(mx, sc[j]);
  }
  float p[MAXL], l = 0.f;
  for (int j = 0; j < MAXL; j++) {
    p[j] = (j < len) ? __expf(sc[j] - mx) : 0.f;
    l += p[j];
  }
  const float rl = 1.f / fmaxf(l, 1e-30f);
  for (int j = 0; j < MAXL; j++) p[j] *= rl;
#pragma unroll
  for (int d = 0; d < 64; d += 8) {
    float acc[8] = {};
    for (int j = 0; j < MAXL; j++) {
      if (j >= len) break;
      short8 v8 = *(const short8*)&QKV[(size_t)(wd * MAXL + j) * QKVS + 2048 + h * 64 + d];
#pragma unroll
      for (int e = 0; e < 8; e++) acc[e] += p[j] * b2f((u16)v8[e]);
    }
    short8 o8;
#pragma unroll
    for (int e = 0; e < 8; e++) o8[e] = (short)f2b(acc[e]);
    *(short8*)&AO[(size_t)(wd * MAXL + i) * 1024 + h * 64 + d] = o8;
  }
}

// ---------------- residual + 4 split-K bf16 partials + bias + LayerNorm ----------------
__global__ __launch_bounds__(256) void ln_resid4(const float* __restrict__ X,
                                                 const u16* __restrict__ P,
                                                 size_t pstride,
                                                 const float* __restrict__ bias,
                                                 const float* __restrict__ g,
                                                 const float* __restrict__ be,
                                                 float* __restrict__ Xo, u16* __restrict__ Xb) {
  const int row = blockIdx.x, t = threadIdx.x;
  const size_t base = (size_t)row * 1024 + t * 4;
  float4 x4 = *(const float4*)&X[base];
  float4 bb = *(const float4*)&bias[t * 4];
  float v[4] = { x4.x + bb.x, x4.y + bb.y, x4.z + bb.z, x4.w + bb.w };
#pragma unroll
  for (int k = 0; k < 4; k++) {
    short4v pk = *(const short4v*)&P[base + k * pstride];
    v[0] += b2f((u16)pk[0]);
    v[1] += b2f((u16)pk[1]);
    v[2] += b2f((u16)pk[2]);
    v[3] += b2f((u16)pk[3]);
  }
  float s = v[0] + v[1] + v[2] + v[3];
  float q = v[0] * v[0] + v[1] * v[1] + v[2] * v[2] + v[3] * v[3];
#pragma unroll
  for (int d = 1; d < 64; d <<= 1) { s += __shfl_xor(s, d); q += __shfl_xor(q, d); }
  __shared__ float ss[4], qq[4];
  if ((t & 63) == 0) { ss[t >> 6] = s; qq[t >> 6] = q; }
  __syncthreads();
  s = ss[0] + ss[1] + ss[2] + ss[3];
  q = qq[0] + qq[1] + qq[2] + qq[3];
  const float mean = s * (1.f / 1024.f);
  const float var = q * (1.f / 1024.f) - mean * mean;
  const float rstd = rsqrtf(var + 1e-5f);
  float4 gv = *(const float4*)&g[t * 4];
  float4 bv = *(const float4*)&be[t * 4];
  float y[4];
  y[0] = (v[0] - mean) * rstd * gv.x + bv.x;
  y[1] = (v[1] - mean) * rstd * gv.y + bv.y;
  y[2] = (v[2] - mean) * rstd * gv.z + bv.z;
  y[3] = (v[3] - mean) * rstd * gv.w + bv.w;
  *(float4*)&Xo[base] = make_float4(y[0], y[1], y[2], y[3]);
  short4v o = { (short)f2b(y[0]), (short)f2b(y[1]), (short)f2b(y[2]), (short)f2b(y[3]) };
  *(short4v*)&Xb[base] = o;
}

// ---------------- misc small kernels ----------------
__global__ __launch_bounds__(256) void posadd(const float* __restrict__ enc,
                                              const float* __restrict__ pos,
                                              float* __restrict__ X, u16* __restrict__ Xb) {
  const int row = blockIdx.x, t = threadIdx.x;
  const int sp = row & 255;
  const size_t base = (size_t)row * 1024 + t * 4;
  float4 e = *(const float4*)&enc[base];
  float4 p = *(const float4*)&pos[(size_t)sp * 1024 + t * 4];
  float y[4] = { e.x + p.x, e.y + p.y, e.z + p.z, e.w + p.w };
  *(float4*)&X[base] = make_float4(y[0], y[1], y[2], y[3]);
  short4v o = { (short)f2b(y[0]), (short)f2b(y[1]), (short)f2b(y[2]), (short)f2b(y[3]) };
  *(short4v*)&Xb[base] = o;
}

__global__ void scan_words(const int* __restrict__ labels, int* __restrict__ t2w,
                           int* __restrict__ t2s, int* __restrict__ wlen) {
  __shared__ int rowEnds[16], rowBase[16];
  const int t = threadIdx.x;
  if (t < 16) {
    int c = 0;
    for (int s = 0; s < 256; s++) c += (labels[t * 256 + s] == 2);
    rowEnds[t] = c;
  }
  __syncthreads();
  if (t == 0) {
    int acc = 0;
    for (int b2 = 0; b2 < 16; b2++) { rowBase[b2] = acc; acc += rowEnds[b2]; }
  }
  __syncthreads();
  if (t < 16) {
    int wc = rowBase[t], fr = 0;
    for (int s = 0; s < 256; s++) {
      const int tok = t * 256 + s, lb = labels[tok];
      if (lb == 1) { fr++; t2w[tok] = wc; t2s[tok] = fr; }
      else if (lb == 2) { t2w[tok] = wc; t2s[tok] = fr + 1; wlen[wc] = fr + 3; wc++; fr = 0; }
      else { t2w[tok] = -1; t2s[tok] = 0; fr = 0; }
    }
  }
}

__global__ __launch_bounds__(256) void build_winp(const float* __restrict__ pos,
                                                  const float* __restrict__ spec,
                                                  const int* __restrict__ wlen,
                                                  float* __restrict__ XW,
                                                  u16* __restrict__ Xb) {
  const int row = blockIdx.x;
  const int wd = row / MAXL, sl = row % MAXL;
  const int len = wlen[wd];
  const int t = threadIdx.x;
  const size_t cb = t * 4;
  float4 p = *(const float4*)&pos[(size_t)sl * 1024 + cb];
  float4 e = make_float4(0.f, 0.f, 0.f, 0.f);
  if (sl == 0) e = *(const float4*)&spec[cb];
  else if (sl == len - 1) e = *(const float4*)&spec[1024 + cb];
  float y[4] = { p.x + e.x, p.y + e.y, p.z + e.z, p.w + e.w };
  *(float4*)&XW[(size_t)row * 1024 + cb] = make_float4(y[0], y[1], y[2], y[3]);
  short4v o = { (short)f2b(y[0]), (short)f2b(y[1]), (short)f2b(y[2]), (short)f2b(y[3]) };
  *(short4v*)&Xb[(size_t)row * 1024 + cb] = o;
}

__global__ __launch_bounds__(256) void scatter_tokens(const float* __restrict__ Xc,
                                                      const int* __restrict__ t2w,
                                                      const int* __restrict__ t2s,
                                                      float* __restrict__ XW,
                                                      u16* __restrict__ Xb) {
  const int tok = blockIdx.x;
  const int wd = t2w[tok];
  if (wd < 0) return;
  const int row = wd * MAXL + t2s[tok];
  const size_t cb = threadIdx.x * 4;
  float4 a = *(const float4*)&Xc[(size_t)tok * 1024 + cb];
  float* dst = &XW[(size_t)row * 1024 + cb];
  float4 b2 = *(const float4*)dst;
  float y[4] = { a.x + b2.x, a.y + b2.y, a.z + b2.z, a.w + b2.w };
  *(float4*)dst = make_float4(y[0], y[1], y[2], y[3]);
  short4v o = { (short)f2b(y[0]), (short)f2b(y[1]), (short)f2b(y[2]), (short)f2b(y[3]) };
  *(short4v*)&Xb[(size_t)row * 1024 + cb] = o;
}

__global__ __launch_bounds__(256) void gather_out(const float* __restrict__ XW,
                                                  float* __restrict__ out) {
  const int wd = blockIdx.x;
  const size_t cb = threadIdx.x * 4;
  *(float4*)&out[(size_t)wd * 1024 + cb] =
      *(const float4*)&XW[(size_t)(wd * MAXL) * 1024 + cb];
}

// ---------------- host side ----------------
extern "C" void kernel_launch(void* const* d_in, const int* in_sizes, int n_in,
                              void* d_out, int out_size, void* d_ws, size_t ws_size,
                              hipStream_t stream) {
  const float* encoded = (const float*)d_in[0];
  const int* lengths = (const int*)d_in[1];
  const int* labels = (const int*)d_in[2];
  const float* pos = (const float*)d_in[4];
  const float* spec = (const float*)d_in[5];
  const float* W[2][16];
  for (int p = 0; p < 2; p++)
    for (int i = 0; i < 16; i++) W[p][i] = (const float*)d_in[6 + p * 16 + i];

  const int NW = out_size / D;  // 1024 words
  const int Mw = NW * MAXL;     // 6144 word-slot rows

  char* wp = (char*)d_ws;
  size_t off = 0;
  auto alloc = [&](size_t bytes) {
    void* r = wp + off;
    off += (bytes + 255) & ~(size_t)255;
    return r;
  };
  float* x_ctx = (float*)alloc((size_t)Mc * D * 4);
  float* x_word = (float*)alloc((size_t)Mw * D * 4);
  u16* xb = (u16*)alloc((size_t)Mw * D * 2);
  u16* wtQKV = (u16*)alloc((size_t)3 * D * D * 2);
  u16* wtO = (u16*)alloc((size_t)D * D * 2);
  u16* wtW1 = (u16*)alloc((size_t)D * FF * 2);
  u16* wtW2 = (u16*)alloc((size_t)D * FF * 2);
  char* uni = (char*)alloc((size_t)Mw * FF * 2);  // QKV(36MB)+Vt(8MB) | hb(48MB)
  u16* QKV = (u16*)uni;
  u16* Vt = (u16*)(uni + ((size_t)40 << 20));
  u16* hb = (u16*)uni;
  u16* AOb = (u16*)alloc((size_t)Mw * D * 2);
  u16* tmpb = (u16*)alloc((size_t)4 * Mw * D * 2);  // 4 split-K bf16 partials
  int* t2w = (int*)alloc((size_t)Mc * 4);
  int* t2s = (int*)alloc((size_t)Mc * 4);
  int* wlen = (int*)alloc((size_t)NW * 4);
  (void)ws_size; (void)in_sizes; (void)n_in;

  posadd<<<Mc, 256, 0, stream>>>(encoded, pos, x_ctx, xb);

  auto run_encoder = [&](int p, float* X, int M, bool is_ctx) {
    for (int l = 0; l < LYR; l++) {
      const size_t oDD = (size_t)l * D * D, oDF = (size_t)l * D * FF;
      TBatch tb;
      tb.src[0] = W[p][0] + oDD; tb.dst[0] = wtQKV;               tb.Kd[0] = D;  tb.Nd[0] = D;
      tb.src[1] = W[p][1] + oDD; tb.dst[1] = wtQKV + (size_t)D * D;   tb.Kd[1] = D;  tb.Nd[1] = D;
      tb.src[2] = W[p][2] + oDD; tb.dst[2] = wtQKV + (size_t)2 * D * D; tb.Kd[2] = D; tb.Nd[2] = D;
      tb.src[3] = W[p][3] + oDD; tb.dst[3] = wtO;                 tb.Kd[3] = D;  tb.Nd[3] = D;
      tb.src[4] = W[p][11] + oDF; tb.dst[4] = wtW1;               tb.Kd[4] = D;  tb.Nd[4] = FF;
      tb.src[5] = W[p][13] + oDF; tb.dst[5] = wtW2;               tb.Kd[5] = FF; tb.Nd[5] = D;
      int base = 0;
      for (int i = 0; i < 6; i++) {
        tb.base[i] = base;
        base += (tb.Kd[i] / 64) * (tb.Nd[i] / 64);
      }
      transpose_batch<<<base, 256, 0, stream>>>(tb, 0);

      // fused QKV projection (128x256 kernel; grids 384/576)
      gemm_qkv<<<(3 * D / 256) * (M / 128), 256, 0, stream>>>(
          xb, wtQKV, W[p][4] + (size_t)l * D, W[p][5] + (size_t)l * D,
          W[p][6] + (size_t)l * D, QKV, M, 3 * D, D, D, 3 * D / 256);
      if (is_ctx) {
        transpose_v<<<dim3(4, H, B), 256, 0, stream>>>(QKV, Vt);
        attn_ctx<<<dim3(4, H, B), 256, 0, stream>>>(QKV, Vt, AOb, lengths);
      } else {
        attn_word<<<(NW * H * MAXL + 255) / 256, 256, 0, stream>>>(QKV, wlen, AOb, NW);
      }
      // O projection: 256² single-buffer, splitK=4 (grids 256/384)
      gemm_bt2s<3, 4><<<4 * (D / 256) * (M / 256), 512, 0, stream>>>(
          AOb, wtO, nullptr, tmpb, M, D, 256, D, D / 256);
      ln_resid4<<<M, 256, 0, stream>>>(X, tmpb, (size_t)M * D, W[p][7] + (size_t)l * D,
                                       W[p][14] + (size_t)l * D, W[p][9] + (size_t)l * D, X, xb);
      // FFN1: 256² single-buffer (bias+relu in-GEMM; grids 256/384)
      gemm_bt2s<2, 0><<<(FF / 256) * (M / 256), 512, 0, stream>>>(
          xb, wtW1, W[p][12] + (size_t)l * FF, hb, M, FF, D, D, FF / 256);
      // FFN2: 256² single-buffer, splitK=4
      gemm_bt2s<3, 4><<<4 * (D / 256) * (M / 256), 512, 0, stream>>>(
          hb, wtW2, nullptr, tmpb, M, D, 1024, FF, D / 256);
      ln_resid4<<<M, 256, 0, stream>>>(X, tmpb, (size_t)M * D, W[p][8] + (size_t)l * D,
                                       W[p][15] + (size_t)l * D, W[p][10] + (size_t)l * D, X, xb);
    }
  };

  run_encoder(0, x_ctx, Mc, true);

  scan_words<<<1, 64, 0, stream>>>(labels, t2w, t2s, wlen);
  build_winp<<<Mw, 256, 0, stream>>>(pos, spec, wlen, x_word, xb);
  scatter_tokens<<<Mc, 256, 0, stream>>>(x_ctx, t2w, t2s, x_word, xb);

  run_encoder(1, x_word, Mw, false);

  gather_out<<<NW, 256, 0, stream>>>(x_word, (float*)d_out);
}

// Round 13
// 1021.261 us; speedup vs baseline: 4.9130x; 1.1594x over previous
//
#include <hip/hip_runtime.h>
#include <stdint.h>

typedef unsigned short u16;
typedef __attribute__((ext_vector_type(8))) short short8;
typedef __attribute__((ext_vector_type(4))) short short4v;
typedef __attribute__((ext_vector_type(4))) float f32x4;

#define DEV static __device__ __forceinline__

constexpr int B = 16, S = 256, D = 1024, H = 16, LYR = 2, FF = 4096;
constexpr int Mc = B * S;
constexpr int MAXL = 6;
constexpr int QKVS = 3 * D;

DEV u16 f2b(float f) {
  union { float f; uint32_t u; } a; a.f = f;
  uint32_t r = a.u + 0x7fffu + ((a.u >> 16) & 1u);
  return (u16)(r >> 16);
}
DEV float b2f(u16 b) {
  union { uint32_t u; float f; } a; a.u = ((uint32_t)b) << 16;
  return a.f;
}

DEV void glds16(const u16* g, u16* l) {
  __builtin_amdgcn_global_load_lds((const __attribute__((address_space(1))) void*)g,
                                   (__attribute__((address_space(3))) void*)l, 16, 0, 0);
}

// ---------------- batched weight transpose: 6 x (W[K][N] f32 -> Wt[N][K] bf16) ----------------
struct TBatch {
  const float* src[6];
  u16* dst[6];
  int Kd[6];
  int Nd[6];
  int base[6];
};

__global__ __launch_bounds__(256) void transpose_batch(TBatch tb, int unused) {
  __shared__ float tile[64][65];
  const int bid = blockIdx.x;
  int wi = 0;
#pragma unroll
  for (int i = 1; i < 6; i++)
    if (bid >= tb.base[i]) wi = i;
  const float* __restrict__ W = tb.src[wi];
  u16* __restrict__ Wt = tb.dst[wi];
  const int K = tb.Kd[wi], N = tb.Nd[wi];
  const int local = bid - tb.base[wi];
  const int ntx = N >> 6;
  const int bn = (local % ntx) * 64, bk = (local / ntx) * 64;
  const int t = threadIdx.x;
  const int lr = t >> 2, lc = (t & 3) * 16;
#pragma unroll
  for (int q = 0; q < 4; q++) {
    float4 v = *(const float4*)&W[(size_t)(bk + lr) * N + bn + lc + q * 4];
    *(float4*)&tile[lr][lc + q * 4] = v;
  }
  __syncthreads();
  const int k0 = (t & 7) * 8;
#pragma unroll
  for (int p = 0; p < 2; p++) {
    const int n = (t >> 3) + p * 32;
    short8 o;
#pragma unroll
    for (int j = 0; j < 8; j++) o[j] = (short)f2b(tile[k0 + j][n]);
    *(short8*)&Wt[(size_t)(bn + n) * K + bk + k0] = o;
  }
}

// ---- bf16 MFMA GEMM (R8 proven optimum): 128x256, 4 waves, BK=64, single-buffer 2-phase,
// T2 both-sides chunk swizzle, T1 XCD chunked swizzle, ~3 blocks/CU inter-block overlap ----
// EPI: 0 = f32+bias, 1 = bf16+bias (SPLITB), 2 = relu->bf16+bias, 3 = bf16 partial.
// SPLITK: grid doubled, upper half at K-offset K, writes partial + M*N.

template <int PASSES>
DEV void stage_rows(const u16* P, int lda, int k0, u16* Dst, int t) {
#pragma unroll
  for (int p = 0; p < PASSES; p++)
    glds16(P + (size_t)(p * 32) * lda + k0, Dst + p * 2048 + t * 8);
}

DEV void compute_tile(const u16* Asb, const u16* Bsb, f32x4 (&acc)[4][8],
                      int wm, int wn, int li, int hi) {
#pragma unroll
  for (int ks = 0; ks < 2; ks++) {
    const int ch = ((((ks << 2) | hi) ^ (li & 7)) * 8);
    short8 af[4], bfr[8];
#pragma unroll
    for (int i = 0; i < 4; i++)
      af[i] = *(const short8*)&Asb[(wm + i * 16 + li) * 64 + ch];
#pragma unroll
    for (int j = 0; j < 8; j++)
      bfr[j] = *(const short8*)&Bsb[(wn + j * 16 + li) * 64 + ch];
#pragma unroll
    for (int i = 0; i < 4; i++)
#pragma unroll
      for (int j = 0; j < 8; j++)
        acc[i][j] = __builtin_amdgcn_mfma_f32_16x16x32_bf16(af[i], bfr[j], acc[i][j], 0, 0, 0);
  }
}

template <int EPI, bool SPLITB, bool SPLITK>
__global__ __launch_bounds__(256, 2) void gemm_bt(const u16* __restrict__ A,
                                                  const u16* __restrict__ Bt,
                                                  const float* __restrict__ bias0,
                                                  const float* __restrict__ bias1,
                                                  const float* __restrict__ bias2,
                                                  float* __restrict__ Cf, u16* __restrict__ Cb,
                                                  int M, int N, int K, int lda, int NB) {
  __shared__ u16 As[128 * 64];
  __shared__ u16 Bs[256 * 64];
  const int t = threadIdx.x, lane = t & 63, w = t >> 6;
  const int wm = (w >> 1) * 64, wn = (w & 1) * 128;
  const int nwg = gridDim.x;
  const int cpx = nwg >> 3;
  const int swz = (blockIdx.x & 7) * cpx + (blockIdx.x >> 3);
  int sblk = 0, rem = swz;
  if (SPLITK) {
    const int tps = nwg >> 1;
    sblk = (swz >= tps) ? 1 : 0;
    rem = swz - sblk * tps;
  }
  const int n0 = (rem % NB) * 256, m0 = (rem / NB) * 128;
  const int pr = t >> 3;
  const int scb = (((t & 7) ^ (pr & 7)) * 8);
  f32x4 acc[4][8] = {};
  const u16* Ap = A + (size_t)sblk * K + (size_t)(m0 + pr) * lda + scb;
  const u16* Bp = Bt + (size_t)sblk * K + (size_t)(n0 + pr) * lda + scb;
  const int li = lane & 15, hi = lane >> 4;

  for (int k0 = 0; k0 < K; k0 += 64) {
    stage_rows<4>(Ap, lda, k0, &As[0], t);
    stage_rows<8>(Bp, lda, k0, &Bs[0], t);
    __syncthreads();  // drains vmcnt; staged tile visible
    compute_tile(&As[0], &Bs[0], acc, wm, wn, li, hi);
    __syncthreads();  // all waves done reading before next overwrite
  }

  u16* Cbs = Cb;
  if (SPLITK && EPI == 3) Cbs = Cb + (size_t)sblk * M * N;
  const int rg = hi * 4;
#pragma unroll
  for (int j = 0; j < 8; j++) {
    const int col = n0 + wn + j * 16 + li;
    float bv = 0.f;
    if (EPI != 3)
      bv = SPLITB ? (col < 1024 ? bias0 : col < 2048 ? bias1 : bias2)[col & 1023]
                  : bias0[col];
#pragma unroll
    for (int i = 0; i < 4; i++) {
      const int row0 = m0 + wm + i * 16 + rg;
#pragma unroll
      for (int r = 0; r < 4; r++) {
        float v = acc[i][j][r] + bv;
        if (EPI == 2) v = fmaxf(v, 0.f);
        if (EPI == 0) Cf[(size_t)(row0 + r) * N + col] = v;
        else Cbs[(size_t)(row0 + r) * N + col] = f2b(v);
      }
    }
  }
}

// ---------------- per-head V transpose (from fused QKV) ----------------
__global__ __launch_bounds__(256) void transpose_v(const u16* __restrict__ QKV,
                                                   u16* __restrict__ Vt) {
  const int kb = blockIdx.x, h = blockIdx.y, b = blockIdx.z;
  __shared__ u16 tile[64][72];
  const int t = threadIdx.x, lr = t >> 3, lc = (t & 7) * 8;
#pragma unroll
  for (int p = 0; p < 2; p++) {
    int r = lr + p * 32;
    *(short8*)&tile[r][lc] =
        *(const short8*)&QKV[(size_t)(b * 256 + kb * 64 + r) * QKVS + 2048 + h * 64 + lc];
  }
  __syncthreads();
#pragma unroll
  for (int p = 0; p < 2; p++) {
    int hd = lr + p * 32;
    short8 v8;
#pragma unroll
    for (int j = 0; j < 8; j++) v8[j] = (short)tile[lc + j][hd];
    *(short8*)&Vt[(size_t)((b * 16 + h) * 64 + hd) * 256 + kb * 64 + lc] = v8;
  }
}

// ---------------- fused ctx attention ----------------
__global__ __launch_bounds__(256) void attn_ctx(const u16* __restrict__ QKV,
                                                const u16* __restrict__ Vt,
                                                u16* __restrict__ AO,
                                                const int* __restrict__ lengths) {
  const int qt = blockIdx.x, h = blockIdx.y, b = blockIdx.z;
  __shared__ u16 Qs[64 * 64], Ks[64 * 64], Vs[64 * 64], Ps[64 * 64];
  const int t = threadIdx.x, lane = t & 63, w = t >> 6;
  const int len = lengths[b];
  const bool full = (len >= 256);
  const int lr = t >> 3, lc = (t & 7) * 8;
#pragma unroll
  for (int p = 0; p < 2; p++) {
    int r = lr + p * 32;
    *(short8*)&Qs[r * 64 + lc] =
        *(const short8*)&QKV[(size_t)(b * 256 + qt * 64 + r) * QKVS + h * 64 + lc];
  }
  const int li = lane & 15, kk = (lane >> 4) * 8, rg = (lane >> 4) * 4;
  float mrun[4], lrun[4];
  f32x4 oacc[4] = {};
#pragma unroll
  for (int r = 0; r < 4; r++) { mrun[r] = -1e30f; lrun[r] = 0.f; }

  for (int kt = 0; kt < 4; kt++) {
    __syncthreads();
#pragma unroll
    for (int p = 0; p < 2; p++) {
      int r = lr + p * 32;
      *(short8*)&Ks[r * 64 + lc] =
          *(const short8*)&QKV[(size_t)(b * 256 + kt * 64 + r) * QKVS + 1024 + h * 64 + lc];
      *(short8*)&Vs[r * 64 + lc] =
          *(const short8*)&Vt[(size_t)((b * 16 + h) * 64 + r) * 256 + kt * 64 + lc];
    }
    __syncthreads();
    f32x4 s[4] = {};
    short8 aq0 = *(const short8*)&Qs[(w * 16 + li) * 64 + kk];
    short8 aq1 = *(const short8*)&Qs[(w * 16 + li) * 64 + 32 + kk];
    __builtin_amdgcn_s_setprio(1);
#pragma unroll
    for (int fn = 0; fn < 4; fn++) {
      short8 b0 = *(const short8*)&Ks[(fn * 16 + li) * 64 + kk];
      short8 b1 = *(const short8*)&Ks[(fn * 16 + li) * 64 + 32 + kk];
      s[fn] = __builtin_amdgcn_mfma_f32_16x16x32_bf16(aq0, b0, s[fn], 0, 0, 0);
      s[fn] = __builtin_amdgcn_mfma_f32_16x16x32_bf16(aq1, b1, s[fn], 0, 0, 0);
    }
    __builtin_amdgcn_s_setprio(0);
    float pv[4][4];
    if (full) {
#pragma unroll
      for (int r = 0; r < 4; r++) {
        float mx = -1e30f;
#pragma unroll
        for (int fn = 0; fn < 4; fn++) {
          float v = s[fn][r] * 0.125f;
          pv[fn][r] = v;
          mx = fmaxf(mx, v);
        }
#pragma unroll
        for (int d = 1; d < 16; d <<= 1) mx = fmaxf(mx, __shfl_xor(mx, d));
        if (mx > mrun[r] + 8.f) {
          float sf = __expf(mrun[r] - mx);
          mrun[r] = mx;
          lrun[r] *= sf;
#pragma unroll
          for (int fn = 0; fn < 4; fn++) oacc[fn][r] *= sf;
        }
        float rs = 0.f;
#pragma unroll
        for (int fn = 0; fn < 4; fn++) {
          float p = __expf(pv[fn][r] - mrun[r]);
          pv[fn][r] = p;
          rs += p;
        }
#pragma unroll
        for (int d = 1; d < 16; d <<= 1) rs += __shfl_xor(rs, d);
        lrun[r] += rs;
      }
    } else {
#pragma unroll
      for (int r = 0; r < 4; r++) {
        float mx = -1e30f;
#pragma unroll
        for (int fn = 0; fn < 4; fn++) {
          int key = kt * 64 + fn * 16 + li;
          float v = (key < len) ? s[fn][r] * 0.125f : -1e30f;
          pv[fn][r] = v;
          mx = fmaxf(mx, v);
        }
#pragma unroll
        for (int d = 1; d < 16; d <<= 1) mx = fmaxf(mx, __shfl_xor(mx, d));
        float mnew = fmaxf(mrun[r], mx);
        float sf = __expf(mrun[r] - mnew);
        mrun[r] = mnew;
        float rs = 0.f;
#pragma unroll
        for (int fn = 0; fn < 4; fn++) {
          int key = kt * 64 + fn * 16 + li;
          float p = (key < len) ? __expf(pv[fn][r] - mnew) : 0.f;
          pv[fn][r] = p;
          rs += p;
        }
#pragma unroll
        for (int d = 1; d < 16; d <<= 1) rs += __shfl_xor(rs, d);
        lrun[r] = lrun[r] * sf + rs;
#pragma unroll
        for (int fn = 0; fn < 4; fn++) oacc[fn][r] *= sf;
      }
    }
#pragma unroll
    for (int fn = 0; fn < 4; fn++)
#pragma unroll
      for (int r = 0; r < 4; r++)
        Ps[(w * 16 + rg + r) * 64 + fn * 16 + li] = f2b(pv[fn][r]);
    __builtin_amdgcn_s_setprio(1);
#pragma unroll
    for (int ks = 0; ks < 2; ks++) {
      short8 ap = *(const short8*)&Ps[(w * 16 + li) * 64 + ks * 32 + kk];
#pragma unroll
      for (int fn = 0; fn < 4; fn++) {
        short8 bv = *(const short8*)&Vs[(fn * 16 + li) * 64 + ks * 32 + kk];
        oacc[fn] = __builtin_amdgcn_mfma_f32_16x16x32_bf16(ap, bv, oacc[fn], 0, 0, 0);
      }
    }
    __builtin_amdgcn_s_setprio(0);
  }
#pragma unroll
  for (int r = 0; r < 4; r++) {
    float inv = 1.f / fmaxf(lrun[r], 1e-30f);
    int row = b * 256 + qt * 64 + w * 16 + rg + r;
#pragma unroll
    for (int fn = 0; fn < 4; fn++) {
      int col = h * 64 + fn * 16 + li;
      AO[(size_t)row * 1024 + col] = f2b(oacc[fn][r] * inv);
    }
  }
}

// ---------------- word attention ----------------
__global__ __launch_bounds__(256) void attn_word(const u16* __restrict__ QKV,
                                                 const int* __restrict__ wlen,
                                                 u16* __restrict__ AO, int NW) {
  const int idx = blockIdx.x * 256 + threadIdx.x;
  if (idx >= NW * 16 * MAXL) return;
  const int i = idx % MAXL, h = (idx / MAXL) % 16, wd = idx / (MAXL * 16);
  const int len = wlen[wd];
  const size_t rowb = (size_t)(wd * MAXL + i) * QKVS;
  float q[64];
#pragma unroll
  for (int d = 0; d < 64; d += 8) {
    short8 q8 = *(const short8*)&QKV[rowb + h * 64 + d];
#pragma unroll
    for (int e = 0; e < 8; e++) q[d + e] = b2f((u16)q8[e]);
  }
  float sc[MAXL];
  float mx = -1e30f;
  for (int j = 0; j < MAXL; j++) {
    if (j >= len) { sc[j] = -1e30f; continue; }
    const size_t koff = (size_t)(wd * MAXL + j) * QKVS + 1024 + h * 64;
    float dot = 0.f;
#pragma unroll
    for (int d = 0; d < 64; d += 8) {
      short8 k8 = *(const short8*)&QKV[koff + d];
#pragma unroll
      for (int e = 0; e < 8; e++) dot += q[d + e] * b2f((u16)k8[e]);
    }
    sc[j] = dot * 0.125f;
    mx = fmaxf(mx, sc[j]);
  }
  float p[MAXL], l = 0.f;
  for (int j = 0; j < MAXL; j++) {
    p[j] = (j < len) ? __expf(sc[j] - mx) : 0.f;
    l += p[j];
  }
  const float rl = 1.f / fmaxf(l, 1e-30f);
  for (int j = 0; j < MAXL; j++) p[j] *= rl;
#pragma unroll
  for (int d = 0; d < 64; d += 8) {
    float acc[8] = {};
    for (int j = 0; j < MAXL; j++) {
      if (j >= len) break;
      short8 v8 = *(const short8*)&QKV[(size_t)(wd * MAXL + j) * QKVS + 2048 + h * 64 + d];
#pragma unroll
      for (int e = 0; e < 8; e++) acc[e] += p[j] * b2f((u16)v8[e]);
    }
    short8 o8;
#pragma unroll
    for (int e = 0; e < 8; e++) o8[e] = (short)f2b(acc[e]);
    *(short8*)&AO[(size_t)(wd * MAXL + i) * 1024 + h * 64 + d] = o8;
  }
}

// ---------------- residual + 2 split-K bf16 partials + bias + LayerNorm ----------------
__global__ __launch_bounds__(256) void ln_resid2(const float* __restrict__ X,
                                                 const u16* __restrict__ P0,
                                                 const u16* __restrict__ P1,
                                                 const float* __restrict__ bias,
                                                 const float* __restrict__ g,
                                                 const float* __restrict__ be,
                                                 float* __restrict__ Xo, u16* __restrict__ Xb) {
  const int row = blockIdx.x, t = threadIdx.x;
  const size_t base = (size_t)row * 1024 + t * 4;
  float4 x4 = *(const float4*)&X[base];
  short4v p0 = *(const short4v*)&P0[base];
  short4v p1 = *(const short4v*)&P1[base];
  float4 bb = *(const float4*)&bias[t * 4];
  float v[4];
  v[0] = x4.x + b2f((u16)p0[0]) + b2f((u16)p1[0]) + bb.x;
  v[1] = x4.y + b2f((u16)p0[1]) + b2f((u16)p1[1]) + bb.y;
  v[2] = x4.z + b2f((u16)p0[2]) + b2f((u16)p1[2]) + bb.z;
  v[3] = x4.w + b2f((u16)p0[3]) + b2f((u16)p1[3]) + bb.w;
  float s = v[0] + v[1] + v[2] + v[3];
  float q = v[0] * v[0] + v[1] * v[1] + v[2] * v[2] + v[3] * v[3];
#pragma unroll
  for (int d = 1; d < 64; d <<= 1) { s += __shfl_xor(s, d); q += __shfl_xor(q, d); }
  __shared__ float ss[4], qq[4];
  if ((t & 63) == 0) { ss[t >> 6] = s; qq[t >> 6] = q; }
  __syncthreads();
  s = ss[0] + ss[1] + ss[2] + ss[3];
  q = qq[0] + qq[1] + qq[2] + qq[3];
  const float mean = s * (1.f / 1024.f);
  const float var = q * (1.f / 1024.f) - mean * mean;
  const float rstd = rsqrtf(var + 1e-5f);
  float4 gv = *(const float4*)&g[t * 4];
  float4 bv = *(const float4*)&be[t * 4];
  float y[4];
  y[0] = (v[0] - mean) * rstd * gv.x + bv.x;
  y[1] = (v[1] - mean) * rstd * gv.y + bv.y;
  y[2] = (v[2] - mean) * rstd * gv.z + bv.z;
  y[3] = (v[3] - mean) * rstd * gv.w + bv.w;
  *(float4*)&Xo[base] = make_float4(y[0], y[1], y[2], y[3]);
  short4v o = { (short)f2b(y[0]), (short)f2b(y[1]), (short)f2b(y[2]), (short)f2b(y[3]) };
  *(short4v*)&Xb[base] = o;
}

// ---------------- misc small kernels ----------------
__global__ __launch_bounds__(256) void posadd(const float* __restrict__ enc,
                                              const float* __restrict__ pos,
                                              float* __restrict__ X, u16* __restrict__ Xb) {
  const int row = blockIdx.x, t = threadIdx.x;
  const int sp = row & 255;
  const size_t base = (size_t)row * 1024 + t * 4;
  float4 e = *(const float4*)&enc[base];
  float4 p = *(const float4*)&pos[(size_t)sp * 1024 + t * 4];
  float y[4] = { e.x + p.x, e.y + p.y, e.z + p.z, e.w + p.w };
  *(float4*)&X[base] = make_float4(y[0], y[1], y[2], y[3]);
  short4v o = { (short)f2b(y[0]), (short)f2b(y[1]), (short)f2b(y[2]), (short)f2b(y[3]) };
  *(short4v*)&Xb[base] = o;
}

__global__ void scan_words(const int* __restrict__ labels, int* __restrict__ t2w,
                           int* __restrict__ t2s, int* __restrict__ wlen) {
  __shared__ int rowEnds[16], rowBase[16];
  const int t = threadIdx.x;
  if (t < 16) {
    int c = 0;
    for (int s = 0; s < 256; s++) c += (labels[t * 256 + s] == 2);
    rowEnds[t] = c;
  }
  __syncthreads();
  if (t == 0) {
    int acc = 0;
    for (int b2 = 0; b2 < 16; b2++) { rowBase[b2] = acc; acc += rowEnds[b2]; }
  }
  __syncthreads();
  if (t < 16) {
    int wc = rowBase[t], fr = 0;
    for (int s = 0; s < 256; s++) {
      const int tok = t * 256 + s, lb = labels[tok];
      if (lb == 1) { fr++; t2w[tok] = wc; t2s[tok] = fr; }
      else if (lb == 2) { t2w[tok] = wc; t2s[tok] = fr + 1; wlen[wc] = fr + 3; wc++; fr = 0; }
      else { t2w[tok] = -1; t2s[tok] = 0; fr = 0; }
    }
  }
}

__global__ __launch_bounds__(256) void build_winp(const float* __restrict__ pos,
                                                  const float* __restrict__ spec,
                                                  const int* __restrict__ wlen,
                                                  float* __restrict__ XW,
                                                  u16* __restrict__ Xb) {
  const int row = blockIdx.x;
  const int wd = row / MAXL, sl = row % MAXL;
  const int len = wlen[wd];
  const int t = threadIdx.x;
  const size_t cb = t * 4;
  float4 p = *(const float4*)&pos[(size_t)sl * 1024 + cb];
  float4 e = make_float4(0.f, 0.f, 0.f, 0.f);
  if (sl == 0) e = *(const float4*)&spec[cb];
  else if (sl == len - 1) e = *(const float4*)&spec[1024 + cb];
  float y[4] = { p.x + e.x, p.y + e.y, p.z + e.z, p.w + e.w };
  *(float4*)&XW[(size_t)row * 1024 + cb] = make_float4(y[0], y[1], y[2], y[3]);
  short4v o = { (short)f2b(y[0]), (short)f2b(y[1]), (short)f2b(y[2]), (short)f2b(y[3]) };
  *(short4v*)&Xb[(size_t)row * 1024 + cb] = o;
}

__global__ __launch_bounds__(256) void scatter_tokens(const float* __restrict__ Xc,
                                                      const int* __restrict__ t2w,
                                                      const int* __restrict__ t2s,
                                                      float* __restrict__ XW,
                                                      u16* __restrict__ Xb) {
  const int tok = blockIdx.x;
  const int wd = t2w[tok];
  if (wd < 0) return;
  const int row = wd * MAXL + t2s[tok];
  const size_t cb = threadIdx.x * 4;
  float4 a = *(const float4*)&Xc[(size_t)tok * 1024 + cb];
  float* dst = &XW[(size_t)row * 1024 + cb];
  float4 b2 = *(const float4*)dst;
  float y[4] = { a.x + b2.x, a.y + b2.y, a.z + b2.z, a.w + b2.w };
  *(float4*)dst = make_float4(y[0], y[1], y[2], y[3]);
  short4v o = { (short)f2b(y[0]), (short)f2b(y[1]), (short)f2b(y[2]), (short)f2b(y[3]) };
  *(short4v*)&Xb[(size_t)row * 1024 + cb] = o;
}

__global__ __launch_bounds__(256) void gather_out(const float* __restrict__ XW,
                                                  float* __restrict__ out) {
  const int wd = blockIdx.x;
  const size_t cb = threadIdx.x * 4;
  *(float4*)&out[(size_t)wd * 1024 + cb] =
      *(const float4*)&XW[(size_t)(wd * MAXL) * 1024 + cb];
}

// ---------------- host side ----------------
extern "C" void kernel_launch(void* const* d_in, const int* in_sizes, int n_in,
                              void* d_out, int out_size, void* d_ws, size_t ws_size,
                              hipStream_t stream) {
  const float* encoded = (const float*)d_in[0];
  const int* lengths = (const int*)d_in[1];
  const int* labels = (const int*)d_in[2];
  const float* pos = (const float*)d_in[4];
  const float* spec = (const float*)d_in[5];
  const float* W[2][16];
  for (int p = 0; p < 2; p++)
    for (int i = 0; i < 16; i++) W[p][i] = (const float*)d_in[6 + p * 16 + i];

  const int NW = out_size / D;  // 1024 words
  const int Mw = NW * MAXL;     // 6144 word-slot rows

  char* wp = (char*)d_ws;
  size_t off = 0;
  auto alloc = [&](size_t bytes) {
    void* r = wp + off;
    off += (bytes + 255) & ~(size_t)255;
    return r;
  };
  float* x_ctx = (float*)alloc((size_t)Mc * D * 4);
  float* x_word = (float*)alloc((size_t)Mw * D * 4);
  u16* xb = (u16*)alloc((size_t)Mw * D * 2);
  u16* wtQKV = (u16*)alloc((size_t)3 * D * D * 2);
  u16* wtO = (u16*)alloc((size_t)D * D * 2);
  u16* wtW1 = (u16*)alloc((size_t)D * FF * 2);
  u16* wtW2 = (u16*)alloc((size_t)D * FF * 2);
  char* uni = (char*)alloc((size_t)Mw * FF * 2);  // QKV(36MB)+Vt(8MB) | hb(48MB)
  u16* QKV = (u16*)uni;
  u16* Vt = (u16*)(uni + ((size_t)40 << 20));
  u16* hb = (u16*)uni;
  u16* AOb = (u16*)alloc((size_t)Mw * D * 2);
  u16* tmpb = (u16*)alloc((size_t)2 * Mw * D * 2);  // 2 split-K bf16 partials
  int* t2w = (int*)alloc((size_t)Mc * 4);
  int* t2s = (int*)alloc((size_t)Mc * 4);
  int* wlen = (int*)alloc((size_t)NW * 4);
  (void)ws_size; (void)in_sizes; (void)n_in;

  posadd<<<Mc, 256, 0, stream>>>(encoded, pos, x_ctx, xb);

  auto run_encoder = [&](int p, float* X, int M, bool is_ctx) {
    for (int l = 0; l < LYR; l++) {
      const size_t oDD = (size_t)l * D * D, oDF = (size_t)l * D * FF;
      TBatch tb;
      tb.src[0] = W[p][0] + oDD; tb.dst[0] = wtQKV;               tb.Kd[0] = D;  tb.Nd[0] = D;
      tb.src[1] = W[p][1] + oDD; tb.dst[1] = wtQKV + (size_t)D * D;   tb.Kd[1] = D;  tb.Nd[1] = D;
      tb.src[2] = W[p][2] + oDD; tb.dst[2] = wtQKV + (size_t)2 * D * D; tb.Kd[2] = D; tb.Nd[2] = D;
      tb.src[3] = W[p][3] + oDD; tb.dst[3] = wtO;                 tb.Kd[3] = D;  tb.Nd[3] = D;
      tb.src[4] = W[p][11] + oDF; tb.dst[4] = wtW1;               tb.Kd[4] = D;  tb.Nd[4] = FF;
      tb.src[5] = W[p][13] + oDF; tb.dst[5] = wtW2;               tb.Kd[5] = FF; tb.Nd[5] = D;
      int base = 0;
      for (int i = 0; i < 6; i++) {
        tb.base[i] = base;
        base += (tb.Kd[i] / 64) * (tb.Nd[i] / 64);
      }
      transpose_batch<<<base, 256, 0, stream>>>(tb, 0);

      // fused QKV projection: [M][3072] (bias in-GEMM)
      gemm_bt<1, true, false><<<(3 * D / 256) * (M / 128), 256, 0, stream>>>(
          xb, wtQKV, W[p][4] + (size_t)l * D, W[p][5] + (size_t)l * D,
          W[p][6] + (size_t)l * D, nullptr, QKV, M, 3 * D, D, D, 3 * D / 256);
      if (is_ctx) {
        transpose_v<<<dim3(4, H, B), 256, 0, stream>>>(QKV, Vt);
        attn_ctx<<<dim3(4, H, B), 256, 0, stream>>>(QKV, Vt, AOb, lengths);
      } else {
        attn_word<<<(NW * H * MAXL + 255) / 256, 256, 0, stream>>>(QKV, wlen, AOb, NW);
      }
      // O projection: split-K=2 in ONE dispatch, bf16 partials
      gemm_bt<3, false, true><<<2 * (D / 256) * (M / 128), 256, 0, stream>>>(
          AOb, wtO, nullptr, nullptr, nullptr, nullptr, tmpb, M, D, 512, D, D / 256);
      ln_resid2<<<M, 256, 0, stream>>>(X, tmpb, tmpb + (size_t)M * D, W[p][7] + (size_t)l * D,
                                       W[p][14] + (size_t)l * D, W[p][9] + (size_t)l * D, X, xb);
      // FFN1 (bias+relu in-GEMM)
      gemm_bt<2, false, false><<<(FF / 256) * (M / 128), 256, 0, stream>>>(
          xb, wtW1, W[p][12] + (size_t)l * FF, nullptr, nullptr, nullptr, hb, M, FF, D, D,
          FF / 256);
      // FFN2: split-K=2 in ONE dispatch, bf16 partials
      gemm_bt<3, false, true><<<2 * (D / 256) * (M / 128), 256, 0, stream>>>(
          hb, wtW2, nullptr, nullptr, nullptr, nullptr, tmpb, M, D, 2048, FF, D / 256);
      ln_resid2<<<M, 256, 0, stream>>>(X, tmpb, tmpb + (size_t)M * D, W[p][8] + (size_t)l * D,
                                       W[p][15] + (size_t)l * D, W[p][10] + (size_t)l * D, X, xb);
    }
  };

  run_encoder(0, x_ctx, Mc, true);

  scan_words<<<1, 64, 0, stream>>>(labels, t2w, t2s, wlen);
  build_winp<<<Mw, 256, 0, stream>>>(pos, spec, wlen, x_word, xb);
  scatter_tokens<<<Mc, 256, 0, stream>>>(x_ctx, t2w, t2s, x_word, xb);

  run_encoder(1, x_word, Mw, false);

  gather_out<<<NW, 256, 0, stream>>>(x_word, (float*)d_out);
}

// Round 14
// 976.907 us; speedup vs baseline: 5.1361x; 1.0454x over previous
//
#include <hip/hip_runtime.h>
#include <stdint.h>

typedef unsigned short u16;
typedef __attribute__((ext_vector_type(8))) short short8;
typedef __attribute__((ext_vector_type(4))) short short4v;
typedef __attribute__((ext_vector_type(4))) float f32x4;

#define DEV static __device__ __forceinline__

constexpr int B = 16, S = 256, D = 1024, H = 16, LYR = 2, FF = 4096;
constexpr int Mc = B * S;
constexpr int MAXL = 6;
constexpr int QKVS = 3 * D;

DEV u16 f2b(float f) {
  union { float f; uint32_t u; } a; a.f = f;
  uint32_t r = a.u + 0x7fffu + ((a.u >> 16) & 1u);
  return (u16)(r >> 16);
}
DEV float b2f(u16 b) {
  union { uint32_t u; float f; } a; a.u = ((uint32_t)b) << 16;
  return a.f;
}

DEV void glds16(const u16* g, u16* l) {
  __builtin_amdgcn_global_load_lds((const __attribute__((address_space(1))) void*)g,
                                   (__attribute__((address_space(3))) void*)l, 16, 0, 0);
}

// ---------------- batched weight transpose: 6 x (W[K][N] f32 -> Wt[N][K] bf16) ----------------
struct TBatch {
  const float* src[6];
  u16* dst[6];
  int Kd[6];
  int Nd[6];
  int base[6];
};

__global__ __launch_bounds__(256) void transpose_batch(TBatch tb, int unused) {
  __shared__ float tile[64][65];
  const int bid = blockIdx.x;
  int wi = 0;
#pragma unroll
  for (int i = 1; i < 6; i++)
    if (bid >= tb.base[i]) wi = i;
  const float* __restrict__ W = tb.src[wi];
  u16* __restrict__ Wt = tb.dst[wi];
  const int K = tb.Kd[wi], N = tb.Nd[wi];
  const int local = bid - tb.base[wi];
  const int ntx = N >> 6;
  const int bn = (local % ntx) * 64, bk = (local / ntx) * 64;
  const int t = threadIdx.x;
  const int lr = t >> 2, lc = (t & 3) * 16;
#pragma unroll
  for (int q = 0; q < 4; q++) {
    float4 v = *(const float4*)&W[(size_t)(bk + lr) * N + bn + lc + q * 4];
    *(float4*)&tile[lr][lc + q * 4] = v;
  }
  __syncthreads();
  const int k0 = (t & 7) * 8;
#pragma unroll
  for (int p = 0; p < 2; p++) {
    const int n = (t >> 3) + p * 32;
    short8 o;
#pragma unroll
    for (int j = 0; j < 8; j++) o[j] = (short)f2b(tile[k0 + j][n]);
    *(short8*)&Wt[(size_t)(bn + n) * K + bk + k0] = o;
  }
}

// ---- bf16 MFMA GEMM (R8/R12 proven optimum): 128x256, 4 waves, BK=64, single-buffer
// 2-phase, T2 both-sides chunk swizzle, T1 XCD chunked swizzle, ~3 blocks/CU overlap ----
// EPI: 1 = bf16+bias (SPLITB), 2 = relu->bf16+bias, 3 = bf16 partial (no bias).
// SPLITK: grid doubled, upper half at K-offset K, writes partial + M*N.

template <int PASSES>
DEV void stage_rows(const u16* P, int lda, int k0, u16* Dst, int t) {
#pragma unroll
  for (int p = 0; p < PASSES; p++)
    glds16(P + (size_t)(p * 32) * lda + k0, Dst + p * 2048 + t * 8);
}

DEV void compute_tile(const u16* Asb, const u16* Bsb, f32x4 (&acc)[4][8],
                      int wm, int wn, int li, int hi) {
#pragma unroll
  for (int ks = 0; ks < 2; ks++) {
    const int ch = ((((ks << 2) | hi) ^ (li & 7)) * 8);
    short8 af[4], bfr[8];
#pragma unroll
    for (int i = 0; i < 4; i++)
      af[i] = *(const short8*)&Asb[(wm + i * 16 + li) * 64 + ch];
#pragma unroll
    for (int j = 0; j < 8; j++)
      bfr[j] = *(const short8*)&Bsb[(wn + j * 16 + li) * 64 + ch];
#pragma unroll
    for (int i = 0; i < 4; i++)
#pragma unroll
      for (int j = 0; j < 8; j++)
        acc[i][j] = __builtin_amdgcn_mfma_f32_16x16x32_bf16(af[i], bfr[j], acc[i][j], 0, 0, 0);
  }
}

template <int EPI, bool SPLITB, bool SPLITK>
__global__ __launch_bounds__(256, 2) void gemm_bt(const u16* __restrict__ A,
                                                  const u16* __restrict__ Bt,
                                                  const float* __restrict__ bias0,
                                                  const float* __restrict__ bias1,
                                                  const float* __restrict__ bias2,
                                                  u16* __restrict__ Cb,
                                                  int M, int N, int K, int lda, int NB) {
  __shared__ u16 As[128 * 64];
  __shared__ u16 Bs[256 * 64];
  const int t = threadIdx.x, lane = t & 63, w = t >> 6;
  const int wm = (w >> 1) * 64, wn = (w & 1) * 128;
  const int nwg = gridDim.x;
  const int cpx = nwg >> 3;
  const int swz = (blockIdx.x & 7) * cpx + (blockIdx.x >> 3);
  int sblk = 0, rem = swz;
  if (SPLITK) {
    const int tps = nwg >> 1;
    sblk = (swz >= tps) ? 1 : 0;
    rem = swz - sblk * tps;
  }
  const int n0 = (rem % NB) * 256, m0 = (rem / NB) * 128;
  const int pr = t >> 3;
  const int scb = (((t & 7) ^ (pr & 7)) * 8);
  f32x4 acc[4][8] = {};
  const u16* Ap = A + (size_t)sblk * K + (size_t)(m0 + pr) * lda + scb;
  const u16* Bp = Bt + (size_t)sblk * K + (size_t)(n0 + pr) * lda + scb;
  const int li = lane & 15, hi = lane >> 4;

  for (int k0 = 0; k0 < K; k0 += 64) {
    stage_rows<4>(Ap, lda, k0, &As[0], t);
    stage_rows<8>(Bp, lda, k0, &Bs[0], t);
    __syncthreads();  // drains vmcnt; staged tile visible
    compute_tile(&As[0], &Bs[0], acc, wm, wn, li, hi);
    __syncthreads();  // all waves done reading before next overwrite
  }

  u16* Cbs = Cb;
  if (SPLITK && EPI == 3) Cbs = Cb + (size_t)sblk * M * N;
  const int rg = hi * 4;
#pragma unroll
  for (int j = 0; j < 8; j++) {
    const int col = n0 + wn + j * 16 + li;
    float bv = 0.f;
    if (EPI != 3)
      bv = SPLITB ? (col < 1024 ? bias0 : col < 2048 ? bias1 : bias2)[col & 1023]
                  : bias0[col];
#pragma unroll
    for (int i = 0; i < 4; i++) {
      const int row0 = m0 + wm + i * 16 + rg;
#pragma unroll
      for (int r = 0; r < 4; r++) {
        float v = acc[i][j][r] + bv;
        if (EPI == 2) v = fmaxf(v, 0.f);
        Cbs[(size_t)(row0 + r) * N + col] = f2b(v);
      }
    }
  }
}

// ---------------- per-head V transpose (from fused QKV) ----------------
__global__ __launch_bounds__(256) void transpose_v(const u16* __restrict__ QKV,
                                                   u16* __restrict__ Vt) {
  const int kb = blockIdx.x, h = blockIdx.y, b = blockIdx.z;
  __shared__ u16 tile[64][72];
  const int t = threadIdx.x, lr = t >> 3, lc = (t & 7) * 8;
#pragma unroll
  for (int p = 0; p < 2; p++) {
    int r = lr + p * 32;
    *(short8*)&tile[r][lc] =
        *(const short8*)&QKV[(size_t)(b * 256 + kb * 64 + r) * QKVS + 2048 + h * 64 + lc];
  }
  __syncthreads();
#pragma unroll
  for (int p = 0; p < 2; p++) {
    int hd = lr + p * 32;
    short8 v8;
#pragma unroll
    for (int j = 0; j < 8; j++) v8[j] = (short)tile[lc + j][hd];
    *(short8*)&Vt[(size_t)((b * 16 + h) * 64 + hd) * 256 + kb * 64 + lc] = v8;
  }
}

// ---------------- fused ctx attention ----------------
__global__ __launch_bounds__(256) void attn_ctx(const u16* __restrict__ QKV,
                                                const u16* __restrict__ Vt,
                                                u16* __restrict__ AO,
                                                const int* __restrict__ lengths) {
  const int qt = blockIdx.x, h = blockIdx.y, b = blockIdx.z;
  __shared__ u16 Qs[64 * 64], Ks[64 * 64], Vs[64 * 64], Ps[64 * 64];
  const int t = threadIdx.x, lane = t & 63, w = t >> 6;
  const int len = lengths[b];
  const bool full = (len >= 256);
  const int lr = t >> 3, lc = (t & 7) * 8;
#pragma unroll
  for (int p = 0; p < 2; p++) {
    int r = lr + p * 32;
    *(short8*)&Qs[r * 64 + lc] =
        *(const short8*)&QKV[(size_t)(b * 256 + qt * 64 + r) * QKVS + h * 64 + lc];
  }
  const int li = lane & 15, kk = (lane >> 4) * 8, rg = (lane >> 4) * 4;
  float mrun[4], lrun[4];
  f32x4 oacc[4] = {};
#pragma unroll
  for (int r = 0; r < 4; r++) { mrun[r] = -1e30f; lrun[r] = 0.f; }

  for (int kt = 0; kt < 4; kt++) {
    __syncthreads();
#pragma unroll
    for (int p = 0; p < 2; p++) {
      int r = lr + p * 32;
      *(short8*)&Ks[r * 64 + lc] =
          *(const short8*)&QKV[(size_t)(b * 256 + kt * 64 + r) * QKVS + 1024 + h * 64 + lc];
      *(short8*)&Vs[r * 64 + lc] =
          *(const short8*)&Vt[(size_t)((b * 16 + h) * 64 + r) * 256 + kt * 64 + lc];
    }
    __syncthreads();
    f32x4 s[4] = {};
    short8 aq0 = *(const short8*)&Qs[(w * 16 + li) * 64 + kk];
    short8 aq1 = *(const short8*)&Qs[(w * 16 + li) * 64 + 32 + kk];
    __builtin_amdgcn_s_setprio(1);
#pragma unroll
    for (int fn = 0; fn < 4; fn++) {
      short8 b0 = *(const short8*)&Ks[(fn * 16 + li) * 64 + kk];
      short8 b1 = *(const short8*)&Ks[(fn * 16 + li) * 64 + 32 + kk];
      s[fn] = __builtin_amdgcn_mfma_f32_16x16x32_bf16(aq0, b0, s[fn], 0, 0, 0);
      s[fn] = __builtin_amdgcn_mfma_f32_16x16x32_bf16(aq1, b1, s[fn], 0, 0, 0);
    }
    __builtin_amdgcn_s_setprio(0);
    float pv[4][4];
    if (full) {
#pragma unroll
      for (int r = 0; r < 4; r++) {
        float mx = -1e30f;
#pragma unroll
        for (int fn = 0; fn < 4; fn++) {
          float v = s[fn][r] * 0.125f;
          pv[fn][r] = v;
          mx = fmaxf(mx, v);
        }
#pragma unroll
        for (int d = 1; d < 16; d <<= 1) mx = fmaxf(mx, __shfl_xor(mx, d));
        if (mx > mrun[r] + 8.f) {
          float sf = __expf(mrun[r] - mx);
          mrun[r] = mx;
          lrun[r] *= sf;
#pragma unroll
          for (int fn = 0; fn < 4; fn++) oacc[fn][r] *= sf;
        }
        float rs = 0.f;
#pragma unroll
        for (int fn = 0; fn < 4; fn++) {
          float p = __expf(pv[fn][r] - mrun[r]);
          pv[fn][r] = p;
          rs += p;
        }
#pragma unroll
        for (int d = 1; d < 16; d <<= 1) rs += __shfl_xor(rs, d);
        lrun[r] += rs;
      }
    } else {
#pragma unroll
      for (int r = 0; r < 4; r++) {
        float mx = -1e30f;
#pragma unroll
        for (int fn = 0; fn < 4; fn++) {
          int key = kt * 64 + fn * 16 + li;
          float v = (key < len) ? s[fn][r] * 0.125f : -1e30f;
          pv[fn][r] = v;
          mx = fmaxf(mx, v);
        }
#pragma unroll
        for (int d = 1; d < 16; d <<= 1) mx = fmaxf(mx, __shfl_xor(mx, d));
        float mnew = fmaxf(mrun[r], mx);
        float sf = __expf(mrun[r] - mnew);
        mrun[r] = mnew;
        float rs = 0.f;
#pragma unroll
        for (int fn = 0; fn < 4; fn++) {
          int key = kt * 64 + fn * 16 + li;
          float p = (key < len) ? __expf(pv[fn][r] - mnew) : 0.f;
          pv[fn][r] = p;
          rs += p;
        }
#pragma unroll
        for (int d = 1; d < 16; d <<= 1) rs += __shfl_xor(rs, d);
        lrun[r] = lrun[r] * sf + rs;
#pragma unroll
        for (int fn = 0; fn < 4; fn++) oacc[fn][r] *= sf;
      }
    }
#pragma unroll
    for (int fn = 0; fn < 4; fn++)
#pragma unroll
      for (int r = 0; r < 4; r++)
        Ps[(w * 16 + rg + r) * 64 + fn * 16 + li] = f2b(pv[fn][r]);
    __builtin_amdgcn_s_setprio(1);
#pragma unroll
    for (int ks = 0; ks < 2; ks++) {
      short8 ap = *(const short8*)&Ps[(w * 16 + li) * 64 + ks * 32 + kk];
#pragma unroll
      for (int fn = 0; fn < 4; fn++) {
        short8 bv = *(const short8*)&Vs[(fn * 16 + li) * 64 + ks * 32 + kk];
        oacc[fn] = __builtin_amdgcn_mfma_f32_16x16x32_bf16(ap, bv, oacc[fn], 0, 0, 0);
      }
    }
    __builtin_amdgcn_s_setprio(0);
  }
#pragma unroll
  for (int r = 0; r < 4; r++) {
    float inv = 1.f / fmaxf(lrun[r], 1e-30f);
    int row = b * 256 + qt * 64 + w * 16 + rg + r;
#pragma unroll
    for (int fn = 0; fn < 4; fn++) {
      int col = h * 64 + fn * 16 + li;
      AO[(size_t)row * 1024 + col] = f2b(oacc[fn][r] * inv);
    }
  }
}

// ---------------- word attention ----------------
__global__ __launch_bounds__(256) void attn_word(const u16* __restrict__ QKV,
                                                 const int* __restrict__ wlen,
                                                 u16* __restrict__ AO, int NW) {
  const int idx = blockIdx.x * 256 + threadIdx.x;
  if (idx >= NW * 16 * MAXL) return;
  const int i = idx % MAXL, h = (idx / MAXL) % 16, wd = idx / (MAXL * 16);
  const int len = wlen[wd];
  const size_t rowb = (size_t)(wd * MAXL + i) * QKVS;
  float q[64];
#pragma unroll
  for (int d = 0; d < 64; d += 8) {
    short8 q8 = *(const short8*)&QKV[rowb + h * 64 + d];
#pragma unroll
    for (int e = 0; e < 8; e++) q[d + e] = b2f((u16)q8[e]);
  }
  float sc[MAXL];
  float mx = -1e30f;
  for (int j = 0; j < MAXL; j++) {
    if (j >= len) { sc[j] = -1e30f; continue; }
    const size_t koff = (size_t)(wd * MAXL + j) * QKVS + 1024 + h * 64;
    float dot = 0.f;
#pragma unroll
    for (int d = 0; d < 64; d += 8) {
      short8 k8 = *(const short8*)&QKV[koff + d];
#pragma unroll
      for (int e = 0; e < 8; e++) dot += q[d + e] * b2f((u16)k8[e]);
    }
    sc[j] = dot * 0.125f;
    mx = fmaxf(mx, sc[j]);
  }
  float p[MAXL], l = 0.f;
  for (int j = 0; j < MAXL; j++) {
    p[j] = (j < len) ? __expf(sc[j] - mx) : 0.f;
    l += p[j];
  }
  const float rl = 1.f / fmaxf(l, 1e-30f);
  for (int j = 0; j < MAXL; j++) p[j] *= rl;
#pragma unroll
  for (int d = 0; d < 64; d += 8) {
    float acc[8] = {};
    for (int j = 0; j < MAXL; j++) {
      if (j >= len) break;
      short8 v8 = *(const short8*)&QKV[(size_t)(wd * MAXL + j) * QKVS + 2048 + h * 64 + d];
#pragma unroll
      for (int e = 0; e < 8; e++) acc[e] += p[j] * b2f((u16)v8[e]);
    }
    short8 o8;
#pragma unroll
    for (int e = 0; e < 8; e++) o8[e] = (short)f2b(acc[e]);
    *(short8*)&AO[(size_t)(wd * MAXL + i) * 1024 + h * 64 + d] = o8;
  }
}

// ---- residual (bf16 stream) + 2 split-K bf16 partials + bias + LayerNorm ----
// Reads Xin (bf16 residual), writes Xbo (bf16); WF32 also writes f32 (final layer only).
template <bool WF32>
__global__ __launch_bounds__(256) void ln_resid2(const u16* __restrict__ Xin,
                                                 const u16* __restrict__ P0,
                                                 const u16* __restrict__ P1,
                                                 const float* __restrict__ bias,
                                                 const float* __restrict__ g,
                                                 const float* __restrict__ be,
                                                 u16* __restrict__ Xbo,
                                                 float* __restrict__ Xo) {
  const int row = blockIdx.x, t = threadIdx.x;
  const size_t base = (size_t)row * 1024 + t * 4;
  short4v x4 = *(const short4v*)&Xin[base];
  short4v p0 = *(const short4v*)&P0[base];
  short4v p1 = *(const short4v*)&P1[base];
  float4 bb = *(const float4*)&bias[t * 4];
  float v[4];
  v[0] = b2f((u16)x4[0]) + b2f((u16)p0[0]) + b2f((u16)p1[0]) + bb.x;
  v[1] = b2f((u16)x4[1]) + b2f((u16)p0[1]) + b2f((u16)p1[1]) + bb.y;
  v[2] = b2f((u16)x4[2]) + b2f((u16)p0[2]) + b2f((u16)p1[2]) + bb.z;
  v[3] = b2f((u16)x4[3]) + b2f((u16)p0[3]) + b2f((u16)p1[3]) + bb.w;
  float s = v[0] + v[1] + v[2] + v[3];
  float q = v[0] * v[0] + v[1] * v[1] + v[2] * v[2] + v[3] * v[3];
#pragma unroll
  for (int d = 1; d < 64; d <<= 1) { s += __shfl_xor(s, d); q += __shfl_xor(q, d); }
  __shared__ float ss[4], qq[4];
  if ((t & 63) == 0) { ss[t >> 6] = s; qq[t >> 6] = q; }
  __syncthreads();
  s = ss[0] + ss[1] + ss[2] + ss[3];
  q = qq[0] + qq[1] + qq[2] + qq[3];
  const float mean = s * (1.f / 1024.f);
  const float var = q * (1.f / 1024.f) - mean * mean;
  const float rstd = rsqrtf(var + 1e-5f);
  float4 gv = *(const float4*)&g[t * 4];
  float4 bv = *(const float4*)&be[t * 4];
  float y[4];
  y[0] = (v[0] - mean) * rstd * gv.x + bv.x;
  y[1] = (v[1] - mean) * rstd * gv.y + bv.y;
  y[2] = (v[2] - mean) * rstd * gv.z + bv.z;
  y[3] = (v[3] - mean) * rstd * gv.w + bv.w;
  if (WF32) *(float4*)&Xo[base] = make_float4(y[0], y[1], y[2], y[3]);
  short4v o = { (short)f2b(y[0]), (short)f2b(y[1]), (short)f2b(y[2]), (short)f2b(y[3]) };
  *(short4v*)&Xbo[base] = o;
}

// ---------------- misc small kernels (bf16 residual stream) ----------------
__global__ __launch_bounds__(256) void posadd(const float* __restrict__ enc,
                                              const float* __restrict__ pos,
                                              u16* __restrict__ Xb) {
  const int row = blockIdx.x, t = threadIdx.x;
  const int sp = row & 255;
  const size_t base = (size_t)row * 1024 + t * 4;
  float4 e = *(const float4*)&enc[base];
  float4 p = *(const float4*)&pos[(size_t)sp * 1024 + t * 4];
  short4v o = { (short)f2b(e.x + p.x), (short)f2b(e.y + p.y),
                (short)f2b(e.z + p.z), (short)f2b(e.w + p.w) };
  *(short4v*)&Xb[base] = o;
}

__global__ void scan_words(const int* __restrict__ labels, int* __restrict__ t2w,
                           int* __restrict__ t2s, int* __restrict__ wlen) {
  __shared__ int rowEnds[16], rowBase[16];
  const int t = threadIdx.x;
  if (t < 16) {
    int c = 0;
    for (int s = 0; s < 256; s++) c += (labels[t * 256 + s] == 2);
    rowEnds[t] = c;
  }
  __syncthreads();
  if (t == 0) {
    int acc = 0;
    for (int b2 = 0; b2 < 16; b2++) { rowBase[b2] = acc; acc += rowEnds[b2]; }
  }
  __syncthreads();
  if (t < 16) {
    int wc = rowBase[t], fr = 0;
    for (int s = 0; s < 256; s++) {
      const int tok = t * 256 + s, lb = labels[tok];
      if (lb == 1) { fr++; t2w[tok] = wc; t2s[tok] = fr; }
      else if (lb == 2) { t2w[tok] = wc; t2s[tok] = fr + 1; wlen[wc] = fr + 3; wc++; fr = 0; }
      else { t2w[tok] = -1; t2s[tok] = 0; fr = 0; }
    }
  }
}

__global__ __launch_bounds__(256) void build_winp(const float* __restrict__ pos,
                                                  const float* __restrict__ spec,
                                                  const int* __restrict__ wlen,
                                                  u16* __restrict__ Xb) {
  const int row = blockIdx.x;
  const int wd = row / MAXL, sl = row % MAXL;
  const int len = wlen[wd];
  const int t = threadIdx.x;
  const size_t cb = t * 4;
  float4 p = *(const float4*)&pos[(size_t)sl * 1024 + cb];
  float4 e = make_float4(0.f, 0.f, 0.f, 0.f);
  if (sl == 0) e = *(const float4*)&spec[cb];
  else if (sl == len - 1) e = *(const float4*)&spec[1024 + cb];
  short4v o = { (short)f2b(p.x + e.x), (short)f2b(p.y + e.y),
                (short)f2b(p.z + e.z), (short)f2b(p.w + e.w) };
  *(short4v*)&Xb[(size_t)row * 1024 + cb] = o;
}

__global__ __launch_bounds__(256) void scatter_tokens(const u16* __restrict__ XcB,
                                                      const int* __restrict__ t2w,
                                                      const int* __restrict__ t2s,
                                                      u16* __restrict__ XW) {
  const int tok = blockIdx.x;
  const int wd = t2w[tok];
  if (wd < 0) return;
  const int row = wd * MAXL + t2s[tok];
  const size_t cb = threadIdx.x * 4;
  short4v a = *(const short4v*)&XcB[(size_t)tok * 1024 + cb];
  u16* dst = &XW[(size_t)row * 1024 + cb];
  short4v b2 = *(const short4v*)dst;
  short4v o;
#pragma unroll
  for (int e = 0; e < 4; e++) o[e] = (short)f2b(b2f((u16)a[e]) + b2f((u16)b2[e]));
  *(short4v*)dst = o;
}

__global__ __launch_bounds__(256) void gather_out(const float* __restrict__ XW,
                                                  float* __restrict__ out) {
  const int wd = blockIdx.x;
  const size_t cb = threadIdx.x * 4;
  *(float4*)&out[(size_t)wd * 1024 + cb] =
      *(const float4*)&XW[(size_t)(wd * MAXL) * 1024 + cb];
}

// ---------------- host side ----------------
extern "C" void kernel_launch(void* const* d_in, const int* in_sizes, int n_in,
                              void* d_out, int out_size, void* d_ws, size_t ws_size,
                              hipStream_t stream) {
  const float* encoded = (const float*)d_in[0];
  const int* lengths = (const int*)d_in[1];
  const int* labels = (const int*)d_in[2];
  const float* pos = (const float*)d_in[4];
  const float* spec = (const float*)d_in[5];
  const float* W[2][16];
  for (int p = 0; p < 2; p++)
    for (int i = 0; i < 16; i++) W[p][i] = (const float*)d_in[6 + p * 16 + i];

  const int NW = out_size / D;  // 1024 words
  const int Mw = NW * MAXL;     // 6144 word-slot rows

  char* wp = (char*)d_ws;
  size_t off = 0;
  auto alloc = [&](size_t bytes) {
    void* r = wp + off;
    off += (bytes + 255) & ~(size_t)255;
    return r;
  };
  float* x_word = (float*)alloc((size_t)Mw * D * 4);  // f32 only for final output staging
  u16* xb_ctx = (u16*)alloc((size_t)Mc * D * 2);
  u16* xb_word = (u16*)alloc((size_t)Mw * D * 2);
  u16* wtQKV = (u16*)alloc((size_t)3 * D * D * 2);
  u16* wtO = (u16*)alloc((size_t)D * D * 2);
  u16* wtW1 = (u16*)alloc((size_t)D * FF * 2);
  u16* wtW2 = (u16*)alloc((size_t)D * FF * 2);
  char* uni = (char*)alloc((size_t)Mw * FF * 2);  // QKV(36MB)+Vt(8MB) | hb(48MB)
  u16* QKV = (u16*)uni;
  u16* Vt = (u16*)(uni + ((size_t)40 << 20));
  u16* hb = (u16*)uni;
  u16* AOb = (u16*)alloc((size_t)Mw * D * 2);
  u16* tmpb = (u16*)alloc((size_t)2 * Mw * D * 2);  // 2 split-K bf16 partials
  int* t2w = (int*)alloc((size_t)Mc * 4);
  int* t2s = (int*)alloc((size_t)Mc * 4);
  int* wlen = (int*)alloc((size_t)NW * 4);
  (void)ws_size; (void)in_sizes; (void)n_in;

  posadd<<<Mc, 256, 0, stream>>>(encoded, pos, xb_ctx);

  auto run_encoder = [&](int p, u16* xb, int M, bool is_ctx) {
    for (int l = 0; l < LYR; l++) {
      const size_t oDD = (size_t)l * D * D, oDF = (size_t)l * D * FF;
      const bool final_ln = (!is_ctx) && (l == LYR - 1);
      TBatch tb;
      tb.src[0] = W[p][0] + oDD; tb.dst[0] = wtQKV;               tb.Kd[0] = D;  tb.Nd[0] = D;
      tb.src[1] = W[p][1] + oDD; tb.dst[1] = wtQKV + (size_t)D * D;   tb.Kd[1] = D;  tb.Nd[1] = D;
      tb.src[2] = W[p][2] + oDD; tb.dst[2] = wtQKV + (size_t)2 * D * D; tb.Kd[2] = D; tb.Nd[2] = D;
      tb.src[3] = W[p][3] + oDD; tb.dst[3] = wtO;                 tb.Kd[3] = D;  tb.Nd[3] = D;
      tb.src[4] = W[p][11] + oDF; tb.dst[4] = wtW1;               tb.Kd[4] = D;  tb.Nd[4] = FF;
      tb.src[5] = W[p][13] + oDF; tb.dst[5] = wtW2;               tb.Kd[5] = FF; tb.Nd[5] = D;
      int base = 0;
      for (int i = 0; i < 6; i++) {
        tb.base[i] = base;
        base += (tb.Kd[i] / 64) * (tb.Nd[i] / 64);
      }
      transpose_batch<<<base, 256, 0, stream>>>(tb, 0);

      // fused QKV projection: [M][3072] (bias in-GEMM)
      gemm_bt<1, true, false><<<(3 * D / 256) * (M / 128), 256, 0, stream>>>(
          xb, wtQKV, W[p][4] + (size_t)l * D, W[p][5] + (size_t)l * D,
          W[p][6] + (size_t)l * D, QKV, M, 3 * D, D, D, 3 * D / 256);
      if (is_ctx) {
        transpose_v<<<dim3(4, H, B), 256, 0, stream>>>(QKV, Vt);
        attn_ctx<<<dim3(4, H, B), 256, 0, stream>>>(QKV, Vt, AOb, lengths);
      } else {
        attn_word<<<(NW * H * MAXL + 255) / 256, 256, 0, stream>>>(QKV, wlen, AOb, NW);
      }
      // O projection: split-K=2 in ONE dispatch, bf16 partials
      gemm_bt<3, false, true><<<2 * (D / 256) * (M / 128), 256, 0, stream>>>(
          AOb, wtO, nullptr, nullptr, nullptr, tmpb, M, D, 512, D, D / 256);
      ln_resid2<false><<<M, 256, 0, stream>>>(xb, tmpb, tmpb + (size_t)M * D,
                                              W[p][7] + (size_t)l * D, W[p][14] + (size_t)l * D,
                                              W[p][9] + (size_t)l * D, xb, nullptr);
      // FFN1 (bias+relu in-GEMM)
      gemm_bt<2, false, false><<<(FF / 256) * (M / 128), 256, 0, stream>>>(
          xb, wtW1, W[p][12] + (size_t)l * FF, nullptr, nullptr, hb, M, FF, D, D, FF / 256);
      // FFN2: split-K=2 in ONE dispatch, bf16 partials
      gemm_bt<3, false, true><<<2 * (D / 256) * (M / 128), 256, 0, stream>>>(
          hb, wtW2, nullptr, nullptr, nullptr, tmpb, M, D, 2048, FF, D / 256);
      if (final_ln)
        ln_resid2<true><<<M, 256, 0, stream>>>(xb, tmpb, tmpb + (size_t)M * D,
                                               W[p][8] + (size_t)l * D, W[p][15] + (size_t)l * D,
                                               W[p][10] + (size_t)l * D, xb, x_word);
      else
        ln_resid2<false><<<M, 256, 0, stream>>>(xb, tmpb, tmpb + (size_t)M * D,
                                                W[p][8] + (size_t)l * D, W[p][15] + (size_t)l * D,
                                                W[p][10] + (size_t)l * D, xb, nullptr);
    }
  };

  run_encoder(0, xb_ctx, Mc, true);

  scan_words<<<1, 64, 0, stream>>>(labels, t2w, t2s, wlen);
  build_winp<<<Mw, 256, 0, stream>>>(pos, spec, wlen, xb_word);
  scatter_tokens<<<Mc, 256, 0, stream>>>(xb_ctx, t2w, t2s, xb_word);

  run_encoder(1, xb_word, Mw, false);

  gather_out<<<NW, 256, 0, stream>>>(x_word, (float*)d_out);
}

// Round 15
// 913.189 us; speedup vs baseline: 5.4945x; 1.0698x over previous
//
#include <hip/hip_runtime.h>
#include <stdint.h>

typedef unsigned short u16;
typedef __attribute__((ext_vector_type(8))) short short8;
typedef __attribute__((ext_vector_type(4))) short short4v;
typedef __attribute__((ext_vector_type(4))) float f32x4;

#define DEV static __device__ __forceinline__

constexpr int B = 16, S = 256, D = 1024, H = 16, LYR = 2, FF = 4096;
constexpr int Mc = B * S;
constexpr int MAXL = 6;
constexpr int QKVS = 3 * D;

DEV u16 f2b(float f) {
  union { float f; uint32_t u; } a; a.f = f;
  uint32_t r = a.u + 0x7fffu + ((a.u >> 16) & 1u);
  return (u16)(r >> 16);
}
DEV float b2f(u16 b) {
  union { uint32_t u; float f; } a; a.u = ((uint32_t)b) << 16;
  return a.f;
}

DEV void glds16(const u16* g, u16* l) {
  __builtin_amdgcn_global_load_lds((const __attribute__((address_space(1))) void*)g,
                                   (__attribute__((address_space(3))) void*)l, 16, 0, 0);
}

// ---------------- batched weight transpose: 6 x (W[K][N] f32 -> Wt[N][K] bf16) ----------------
struct TBatch {
  const float* src[6];
  u16* dst[6];
  int Kd[6];
  int Nd[6];
  int base[6];
};

__global__ __launch_bounds__(256) void transpose_batch(TBatch tb, int unused) {
  __shared__ float tile[64][65];
  const int bid = blockIdx.x;
  int wi = 0;
#pragma unroll
  for (int i = 1; i < 6; i++)
    if (bid >= tb.base[i]) wi = i;
  const float* __restrict__ W = tb.src[wi];
  u16* __restrict__ Wt = tb.dst[wi];
  const int K = tb.Kd[wi], N = tb.Nd[wi];
  const int local = bid - tb.base[wi];
  const int ntx = N >> 6;
  const int bn = (local % ntx) * 64, bk = (local / ntx) * 64;
  const int t = threadIdx.x;
  const int lr = t >> 2, lc = (t & 3) * 16;
#pragma unroll
  for (int q = 0; q < 4; q++) {
    float4 v = *(const float4*)&W[(size_t)(bk + lr) * N + bn + lc + q * 4];
    *(float4*)&tile[lr][lc + q * 4] = v;
  }
  __syncthreads();
  const int k0 = (t & 7) * 8;
#pragma unroll
  for (int p = 0; p < 2; p++) {
    const int n = (t >> 3) + p * 32;
    short8 o;
#pragma unroll
    for (int j = 0; j < 8; j++) o[j] = (short)f2b(tile[k0 + j][n]);
    *(short8*)&Wt[(size_t)(bn + n) * K + bk + k0] = o;
  }
}

// ---- bf16 MFMA GEMM (proven optimum): 128x256, 4 waves, BK=64, single-buffer 2-phase,
// T2 both-sides chunk swizzle, T1 XCD chunked swizzle. Separate A/B row strides ----
// EPI: 1 = bf16+bias (SPLITB), 2 = relu->bf16+bias, 3 = bf16 partial (no bias).
// SPLITK: grid doubled, upper half at K-offset K, writes partial + M*N.

template <int PASSES>
DEV void stage_rows(const u16* P, int lda, int k0, u16* Dst, int t) {
#pragma unroll
  for (int p = 0; p < PASSES; p++)
    glds16(P + (size_t)(p * 32) * lda + k0, Dst + p * 2048 + t * 8);
}

DEV void compute_tile(const u16* Asb, const u16* Bsb, f32x4 (&acc)[4][8],
                      int wm, int wn, int li, int hi) {
#pragma unroll
  for (int ks = 0; ks < 2; ks++) {
    const int ch = ((((ks << 2) | hi) ^ (li & 7)) * 8);
    short8 af[4], bfr[8];
#pragma unroll
    for (int i = 0; i < 4; i++)
      af[i] = *(const short8*)&Asb[(wm + i * 16 + li) * 64 + ch];
#pragma unroll
    for (int j = 0; j < 8; j++)
      bfr[j] = *(const short8*)&Bsb[(wn + j * 16 + li) * 64 + ch];
#pragma unroll
    for (int i = 0; i < 4; i++)
#pragma unroll
      for (int j = 0; j < 8; j++)
        acc[i][j] = __builtin_amdgcn_mfma_f32_16x16x32_bf16(af[i], bfr[j], acc[i][j], 0, 0, 0);
  }
}

template <int EPI, bool SPLITB, bool SPLITK>
__global__ __launch_bounds__(256, 2) void gemm_bt(const u16* __restrict__ A,
                                                  const u16* __restrict__ Bt,
                                                  const float* __restrict__ bias0,
                                                  const float* __restrict__ bias1,
                                                  const float* __restrict__ bias2,
                                                  u16* __restrict__ Cb,
                                                  int M, int N, int K, int ldaA, int ldaB,
                                                  int NB) {
  __shared__ u16 As[128 * 64];
  __shared__ u16 Bs[256 * 64];
  const int t = threadIdx.x, lane = t & 63, w = t >> 6;
  const int wm = (w >> 1) * 64, wn = (w & 1) * 128;
  const int nwg = gridDim.x;
  const int cpx = nwg >> 3;
  const int swz = (blockIdx.x & 7) * cpx + (blockIdx.x >> 3);
  int sblk = 0, rem = swz;
  if (SPLITK) {
    const int tps = nwg >> 1;
    sblk = (swz >= tps) ? 1 : 0;
    rem = swz - sblk * tps;
  }
  const int n0 = (rem % NB) * 256, m0 = (rem / NB) * 128;
  const int pr = t >> 3;
  const int scb = (((t & 7) ^ (pr & 7)) * 8);
  f32x4 acc[4][8] = {};
  const u16* Ap = A + (size_t)sblk * K + (size_t)(m0 + pr) * ldaA + scb;
  const u16* Bp = Bt + (size_t)sblk * K + (size_t)(n0 + pr) * ldaB + scb;
  const int li = lane & 15, hi = lane >> 4;

  for (int k0 = 0; k0 < K; k0 += 64) {
    stage_rows<4>(Ap, ldaA, k0, &As[0], t);
    stage_rows<8>(Bp, ldaB, k0, &Bs[0], t);
    __syncthreads();  // drains vmcnt; staged tile visible
    compute_tile(&As[0], &Bs[0], acc, wm, wn, li, hi);
    __syncthreads();  // all waves done reading before next overwrite
  }

  u16* Cbs = Cb;
  if (SPLITK && EPI == 3) Cbs = Cb + (size_t)sblk * M * N;
  const int rg = hi * 4;
#pragma unroll
  for (int j = 0; j < 8; j++) {
    const int col = n0 + wn + j * 16 + li;
    float bv = 0.f;
    if (EPI != 3)
      bv = SPLITB ? (col < 1024 ? bias0 : col < 2048 ? bias1 : bias2)[col & 1023]
                  : bias0[col];
#pragma unroll
    for (int i = 0; i < 4; i++) {
      const int row0 = m0 + wm + i * 16 + rg;
#pragma unroll
      for (int r = 0; r < 4; r++) {
        float v = acc[i][j][r] + bv;
        if (EPI == 2) v = fmaxf(v, 0.f);
        Cbs[(size_t)(row0 + r) * N + col] = f2b(v);
      }
    }
  }
}

// ---------------- per-head V transpose (from fused QKV) ----------------
__global__ __launch_bounds__(256) void transpose_v(const u16* __restrict__ QKV,
                                                   u16* __restrict__ Vt) {
  const int kb = blockIdx.x, h = blockIdx.y, b = blockIdx.z;
  __shared__ u16 tile[64][72];
  const int t = threadIdx.x, lr = t >> 3, lc = (t & 7) * 8;
#pragma unroll
  for (int p = 0; p < 2; p++) {
    int r = lr + p * 32;
    *(short8*)&tile[r][lc] =
        *(const short8*)&QKV[(size_t)(b * 256 + kb * 64 + r) * QKVS + 2048 + h * 64 + lc];
  }
  __syncthreads();
#pragma unroll
  for (int p = 0; p < 2; p++) {
    int hd = lr + p * 32;
    short8 v8;
#pragma unroll
    for (int j = 0; j < 8; j++) v8[j] = (short)tile[lc + j][hd];
    *(short8*)&Vt[(size_t)((b * 16 + h) * 64 + hd) * 256 + kb * 64 + lc] = v8;
  }
}

// ---------------- fused ctx attention ----------------
__global__ __launch_bounds__(256) void attn_ctx(const u16* __restrict__ QKV,
                                                const u16* __restrict__ Vt,
                                                u16* __restrict__ AO,
                                                const int* __restrict__ lengths) {
  const int qt = blockIdx.x, h = blockIdx.y, b = blockIdx.z;
  __shared__ u16 Qs[64 * 64], Ks[64 * 64], Vs[64 * 64], Ps[64 * 64];
  const int t = threadIdx.x, lane = t & 63, w = t >> 6;
  const int len = lengths[b];
  const bool full = (len >= 256);
  const int lr = t >> 3, lc = (t & 7) * 8;
#pragma unroll
  for (int p = 0; p < 2; p++) {
    int r = lr + p * 32;
    *(short8*)&Qs[r * 64 + lc] =
        *(const short8*)&QKV[(size_t)(b * 256 + qt * 64 + r) * QKVS + h * 64 + lc];
  }
  const int li = lane & 15, kk = (lane >> 4) * 8, rg = (lane >> 4) * 4;
  float mrun[4], lrun[4];
  f32x4 oacc[4] = {};
#pragma unroll
  for (int r = 0; r < 4; r++) { mrun[r] = -1e30f; lrun[r] = 0.f; }

  for (int kt = 0; kt < 4; kt++) {
    __syncthreads();
#pragma unroll
    for (int p = 0; p < 2; p++) {
      int r = lr + p * 32;
      *(short8*)&Ks[r * 64 + lc] =
          *(const short8*)&QKV[(size_t)(b * 256 + kt * 64 + r) * QKVS + 1024 + h * 64 + lc];
      *(short8*)&Vs[r * 64 + lc] =
          *(const short8*)&Vt[(size_t)((b * 16 + h) * 64 + r) * 256 + kt * 64 + lc];
    }
    __syncthreads();
    f32x4 s[4] = {};
    short8 aq0 = *(const short8*)&Qs[(w * 16 + li) * 64 + kk];
    short8 aq1 = *(const short8*)&Qs[(w * 16 + li) * 64 + 32 + kk];
    __builtin_amdgcn_s_setprio(1);
#pragma unroll
    for (int fn = 0; fn < 4; fn++) {
      short8 b0 = *(const short8*)&Ks[(fn * 16 + li) * 64 + kk];
      short8 b1 = *(const short8*)&Ks[(fn * 16 + li) * 64 + 32 + kk];
      s[fn] = __builtin_amdgcn_mfma_f32_16x16x32_bf16(aq0, b0, s[fn], 0, 0, 0);
      s[fn] = __builtin_amdgcn_mfma_f32_16x16x32_bf16(aq1, b1, s[fn], 0, 0, 0);
    }
    __builtin_amdgcn_s_setprio(0);
    float pv[4][4];
    if (full) {
#pragma unroll
      for (int r = 0; r < 4; r++) {
        float mx = -1e30f;
#pragma unroll
        for (int fn = 0; fn < 4; fn++) {
          float v = s[fn][r] * 0.125f;
          pv[fn][r] = v;
          mx = fmaxf(mx, v);
        }
#pragma unroll
        for (int d = 1; d < 16; d <<= 1) mx = fmaxf(mx, __shfl_xor(mx, d));
        if (mx > mrun[r] + 8.f) {
          float sf = __expf(mrun[r] - mx);
          mrun[r] = mx;
          lrun[r] *= sf;
#pragma unroll
          for (int fn = 0; fn < 4; fn++) oacc[fn][r] *= sf;
        }
        float rs = 0.f;
#pragma unroll
        for (int fn = 0; fn < 4; fn++) {
          float p = __expf(pv[fn][r] - mrun[r]);
          pv[fn][r] = p;
          rs += p;
        }
#pragma unroll
        for (int d = 1; d < 16; d <<= 1) rs += __shfl_xor(rs, d);
        lrun[r] += rs;
      }
    } else {
#pragma unroll
      for (int r = 0; r < 4; r++) {
        float mx = -1e30f;
#pragma unroll
        for (int fn = 0; fn < 4; fn++) {
          int key = kt * 64 + fn * 16 + li;
          float v = (key < len) ? s[fn][r] * 0.125f : -1e30f;
          pv[fn][r] = v;
          mx = fmaxf(mx, v);
        }
#pragma unroll
        for (int d = 1; d < 16; d <<= 1) mx = fmaxf(mx, __shfl_xor(mx, d));
        float mnew = fmaxf(mrun[r], mx);
        float sf = __expf(mrun[r] - mnew);
        mrun[r] = mnew;
        float rs = 0.f;
#pragma unroll
        for (int fn = 0; fn < 4; fn++) {
          int key = kt * 64 + fn * 16 + li;
          float p = (key < len) ? __expf(pv[fn][r] - mnew) : 0.f;
          pv[fn][r] = p;
          rs += p;
        }
#pragma unroll
        for (int d = 1; d < 16; d <<= 1) rs += __shfl_xor(rs, d);
        lrun[r] = lrun[r] * sf + rs;
#pragma unroll
        for (int fn = 0; fn < 4; fn++) oacc[fn][r] *= sf;
      }
    }
#pragma unroll
    for (int fn = 0; fn < 4; fn++)
#pragma unroll
      for (int r = 0; r < 4; r++)
        Ps[(w * 16 + rg + r) * 64 + fn * 16 + li] = f2b(pv[fn][r]);
    __builtin_amdgcn_s_setprio(1);
#pragma unroll
    for (int ks = 0; ks < 2; ks++) {
      short8 ap = *(const short8*)&Ps[(w * 16 + li) * 64 + ks * 32 + kk];
#pragma unroll
      for (int fn = 0; fn < 4; fn++) {
        short8 bv = *(const short8*)&Vs[(fn * 16 + li) * 64 + ks * 32 + kk];
        oacc[fn] = __builtin_amdgcn_mfma_f32_16x16x32_bf16(ap, bv, oacc[fn], 0, 0, 0);
      }
    }
    __builtin_amdgcn_s_setprio(0);
  }
#pragma unroll
  for (int r = 0; r < 4; r++) {
    float inv = 1.f / fmaxf(lrun[r], 1e-30f);
    int row = b * 256 + qt * 64 + w * 16 + rg + r;
#pragma unroll
    for (int fn = 0; fn < 4; fn++) {
      int col = h * 64 + fn * 16 + li;
      AO[(size_t)row * 1024 + col] = f2b(oacc[fn][r] * inv);
    }
  }
}

// ---------------- word attention (full rows; used for word layer 0) ----------------
__global__ __launch_bounds__(256) void attn_word(const u16* __restrict__ QKV,
                                                 const int* __restrict__ wlen,
                                                 u16* __restrict__ AO, int NW) {
  const int idx = blockIdx.x * 256 + threadIdx.x;
  if (idx >= NW * 16 * MAXL) return;
  const int i = idx % MAXL, h = (idx / MAXL) % 16, wd = idx / (MAXL * 16);
  const int len = wlen[wd];
  const size_t rowb = (size_t)(wd * MAXL + i) * QKVS;
  float q[64];
#pragma unroll
  for (int d = 0; d < 64; d += 8) {
    short8 q8 = *(const short8*)&QKV[rowb + h * 64 + d];
#pragma unroll
    for (int e = 0; e < 8; e++) q[d + e] = b2f((u16)q8[e]);
  }
  float sc[MAXL];
  float mx = -1e30f;
  for (int j = 0; j < MAXL; j++) {
    if (j >= len) { sc[j] = -1e30f; continue; }
    const size_t koff = (size_t)(wd * MAXL + j) * QKVS + 1024 + h * 64;
    float dot = 0.f;
#pragma unroll
    for (int d = 0; d < 64; d += 8) {
      short8 k8 = *(const short8*)&QKV[koff + d];
#pragma unroll
      for (int e = 0; e < 8; e++) dot += q[d + e] * b2f((u16)k8[e]);
    }
    sc[j] = dot * 0.125f;
    mx = fmaxf(mx, sc[j]);
  }
  float p[MAXL], l = 0.f;
  for (int j = 0; j < MAXL; j++) {
    p[j] = (j < len) ? __expf(sc[j] - mx) : 0.f;
    l += p[j];
  }
  const float rl = 1.f / fmaxf(l, 1e-30f);
  for (int j = 0; j < MAXL; j++) p[j] *= rl;
#pragma unroll
  for (int d = 0; d < 64; d += 8) {
    float acc[8] = {};
    for (int j = 0; j < MAXL; j++) {
      if (j >= len) break;
      short8 v8 = *(const short8*)&QKV[(size_t)(wd * MAXL + j) * QKVS + 2048 + h * 64 + d];
#pragma unroll
      for (int e = 0; e < 8; e++) acc[e] += p[j] * b2f((u16)v8[e]);
    }
    short8 o8;
#pragma unroll
    for (int e = 0; e < 8; e++) o8[e] = (short)f2b(acc[e]);
    *(short8*)&AO[(size_t)(wd * MAXL + i) * 1024 + h * 64 + d] = o8;
  }
}

// ---- word attention, BOS queries only (word layer 2): compact AO [NW][1024] ----
__global__ __launch_bounds__(256) void attn_word_bos(const u16* __restrict__ QKV,
                                                     const int* __restrict__ wlen,
                                                     u16* __restrict__ AOc, int NW) {
  const int idx = blockIdx.x * 256 + threadIdx.x;
  if (idx >= NW * 16) return;
  const int h = idx % 16, wd = idx / 16;
  const int len = wlen[wd];
  const size_t rowb = (size_t)(wd * MAXL) * QKVS;  // slot 0 query
  float q[64];
#pragma unroll
  for (int d = 0; d < 64; d += 8) {
    short8 q8 = *(const short8*)&QKV[rowb + h * 64 + d];
#pragma unroll
    for (int e = 0; e < 8; e++) q[d + e] = b2f((u16)q8[e]);
  }
  float sc[MAXL];
  float mx = -1e30f;
  for (int j = 0; j < MAXL; j++) {
    if (j >= len) { sc[j] = -1e30f; continue; }
    const size_t koff = (size_t)(wd * MAXL + j) * QKVS + 1024 + h * 64;
    float dot = 0.f;
#pragma unroll
    for (int d = 0; d < 64; d += 8) {
      short8 k8 = *(const short8*)&QKV[koff + d];
#pragma unroll
      for (int e = 0; e < 8; e++) dot += q[d + e] * b2f((u16)k8[e]);
    }
    sc[j] = dot * 0.125f;
    mx = fmaxf(mx, sc[j]);
  }
  float p[MAXL], l = 0.f;
  for (int j = 0; j < MAXL; j++) {
    p[j] = (j < len) ? __expf(sc[j] - mx) : 0.f;
    l += p[j];
  }
  const float rl = 1.f / fmaxf(l, 1e-30f);
  for (int j = 0; j < MAXL; j++) p[j] *= rl;
#pragma unroll
  for (int d = 0; d < 64; d += 8) {
    float acc[8] = {};
    for (int j = 0; j < MAXL; j++) {
      if (j >= len) break;
      short8 v8 = *(const short8*)&QKV[(size_t)(wd * MAXL + j) * QKVS + 2048 + h * 64 + d];
#pragma unroll
      for (int e = 0; e < 8; e++) acc[e] += p[j] * b2f((u16)v8[e]);
    }
    short8 o8;
#pragma unroll
    for (int e = 0; e < 8; e++) o8[e] = (short)f2b(acc[e]);
    *(short8*)&AOc[(size_t)wd * 1024 + h * 64 + d] = o8;
  }
}

// ---- residual (bf16, row-stride RS) + 2 split-K bf16 partials + bias + LayerNorm ----
// Partials/outputs are compact (row*1024). WF32: also write f32 (to d_out for final LN).
template <int RS, bool WF32>
__global__ __launch_bounds__(256) void ln_resid2(const u16* __restrict__ Xin,
                                                 const u16* __restrict__ P0,
                                                 const u16* __restrict__ P1,
                                                 const float* __restrict__ bias,
                                                 const float* __restrict__ g,
                                                 const float* __restrict__ be,
                                                 u16* __restrict__ Xbo,
                                                 float* __restrict__ Xo) {
  const int row = blockIdx.x, t = threadIdx.x;
  const size_t base = (size_t)row * 1024 + t * 4;
  const size_t basein = (size_t)row * RS * 1024 + t * 4;
  short4v x4 = *(const short4v*)&Xin[basein];
  short4v p0 = *(const short4v*)&P0[base];
  short4v p1 = *(const short4v*)&P1[base];
  float4 bb = *(const float4*)&bias[t * 4];
  float v[4];
  v[0] = b2f((u16)x4[0]) + b2f((u16)p0[0]) + b2f((u16)p1[0]) + bb.x;
  v[1] = b2f((u16)x4[1]) + b2f((u16)p0[1]) + b2f((u16)p1[1]) + bb.y;
  v[2] = b2f((u16)x4[2]) + b2f((u16)p0[2]) + b2f((u16)p1[2]) + bb.z;
  v[3] = b2f((u16)x4[3]) + b2f((u16)p0[3]) + b2f((u16)p1[3]) + bb.w;
  float s = v[0] + v[1] + v[2] + v[3];
  float q = v[0] * v[0] + v[1] * v[1] + v[2] * v[2] + v[3] * v[3];
#pragma unroll
  for (int d = 1; d < 64; d <<= 1) { s += __shfl_xor(s, d); q += __shfl_xor(q, d); }
  __shared__ float ss[4], qq[4];
  if ((t & 63) == 0) { ss[t >> 6] = s; qq[t >> 6] = q; }
  __syncthreads();
  s = ss[0] + ss[1] + ss[2] + ss[3];
  q = qq[0] + qq[1] + qq[2] + qq[3];
  const float mean = s * (1.f / 1024.f);
  const float var = q * (1.f / 1024.f) - mean * mean;
  const float rstd = rsqrtf(var + 1e-5f);
  float4 gv = *(const float4*)&g[t * 4];
  float4 bv = *(const float4*)&be[t * 4];
  float y[4];
  y[0] = (v[0] - mean) * rstd * gv.x + bv.x;
  y[1] = (v[1] - mean) * rstd * gv.y + bv.y;
  y[2] = (v[2] - mean) * rstd * gv.z + bv.z;
  y[3] = (v[3] - mean) * rstd * gv.w + bv.w;
  if (WF32) *(float4*)&Xo[base] = make_float4(y[0], y[1], y[2], y[3]);
  short4v o = { (short)f2b(y[0]), (short)f2b(y[1]), (short)f2b(y[2]), (short)f2b(y[3]) };
  *(short4v*)&Xbo[base] = o;
}

// ---------------- misc small kernels (bf16 residual stream) ----------------
__global__ __launch_bounds__(256) void posadd(const float* __restrict__ enc,
                                              const float* __restrict__ pos,
                                              u16* __restrict__ Xb) {
  const int row = blockIdx.x, t = threadIdx.x;
  const int sp = row & 255;
  const size_t base = (size_t)row * 1024 + t * 4;
  float4 e = *(const float4*)&enc[base];
  float4 p = *(const float4*)&pos[(size_t)sp * 1024 + t * 4];
  short4v o = { (short)f2b(e.x + p.x), (short)f2b(e.y + p.y),
                (short)f2b(e.z + p.z), (short)f2b(e.w + p.w) };
  *(short4v*)&Xb[base] = o;
}

__global__ void scan_words(const int* __restrict__ labels, int* __restrict__ t2w,
                           int* __restrict__ t2s, int* __restrict__ wlen) {
  __shared__ int rowEnds[16], rowBase[16];
  const int t = threadIdx.x;
  if (t < 16) {
    int c = 0;
    for (int s = 0; s < 256; s++) c += (labels[t * 256 + s] == 2);
    rowEnds[t] = c;
  }
  __syncthreads();
  if (t == 0) {
    int acc = 0;
    for (int b2 = 0; b2 < 16; b2++) { rowBase[b2] = acc; acc += rowEnds[b2]; }
  }
  __syncthreads();
  if (t < 16) {
    int wc = rowBase[t], fr = 0;
    for (int s = 0; s < 256; s++) {
      const int tok = t * 256 + s, lb = labels[tok];
      if (lb == 1) { fr++; t2w[tok] = wc; t2s[tok] = fr; }
      else if (lb == 2) { t2w[tok] = wc; t2s[tok] = fr + 1; wlen[wc] = fr + 3; wc++; fr = 0; }
      else { t2w[tok] = -1; t2s[tok] = 0; fr = 0; }
    }
  }
}

__global__ __launch_bounds__(256) void build_winp(const float* __restrict__ pos,
                                                  const float* __restrict__ spec,
                                                  const int* __restrict__ wlen,
                                                  u16* __restrict__ Xb) {
  const int row = blockIdx.x;
  const int wd = row / MAXL, sl = row % MAXL;
  const int len = wlen[wd];
  const int t = threadIdx.x;
  const size_t cb = t * 4;
  float4 p = *(const float4*)&pos[(size_t)sl * 1024 + cb];
  float4 e = make_float4(0.f, 0.f, 0.f, 0.f);
  if (sl == 0) e = *(const float4*)&spec[cb];
  else if (sl == len - 1) e = *(const float4*)&spec[1024 + cb];
  short4v o = { (short)f2b(p.x + e.x), (short)f2b(p.y + e.y),
                (short)f2b(p.z + e.z), (short)f2b(p.w + e.w) };
  *(short4v*)&Xb[(size_t)row * 1024 + cb] = o;
}

__global__ __launch_bounds__(256) void scatter_tokens(const u16* __restrict__ XcB,
                                                      const int* __restrict__ t2w,
                                                      const int* __restrict__ t2s,
                                                      u16* __restrict__ XW) {
  const int tok = blockIdx.x;
  const int wd = t2w[tok];
  if (wd < 0) return;
  const int row = wd * MAXL + t2s[tok];
  const size_t cb = threadIdx.x * 4;
  short4v a = *(const short4v*)&XcB[(size_t)tok * 1024 + cb];
  u16* dst = &XW[(size_t)row * 1024 + cb];
  short4v b2 = *(const short4v*)dst;
  short4v o;
#pragma unroll
  for (int e = 0; e < 4; e++) o[e] = (short)f2b(b2f((u16)a[e]) + b2f((u16)b2[e]));
  *(short4v*)dst = o;
}

// ---------------- host side ----------------
extern "C" void kernel_launch(void* const* d_in, const int* in_sizes, int n_in,
                              void* d_out, int out_size, void* d_ws, size_t ws_size,
                              hipStream_t stream) {
  const float* encoded = (const float*)d_in[0];
  const int* lengths = (const int*)d_in[1];
  const int* labels = (const int*)d_in[2];
  const float* pos = (const float*)d_in[4];
  const float* spec = (const float*)d_in[5];
  const float* W[2][16];
  for (int p = 0; p < 2; p++)
    for (int i = 0; i < 16; i++) W[p][i] = (const float*)d_in[6 + p * 16 + i];

  const int NW = out_size / D;  // 1024 words
  const int Mw = NW * MAXL;     // 6144 word-slot rows

  char* wp = (char*)d_ws;
  size_t off = 0;
  auto alloc = [&](size_t bytes) {
    void* r = wp + off;
    off += (bytes + 255) & ~(size_t)255;
    return r;
  };
  u16* xb_ctx = (u16*)alloc((size_t)Mc * D * 2);
  u16* xb_word = (u16*)alloc((size_t)Mw * D * 2);
  u16* xc = (u16*)alloc((size_t)NW * D * 2);  // compact word-l2 activations
  u16* wtQKV = (u16*)alloc((size_t)3 * D * D * 2);
  u16* wtO = (u16*)alloc((size_t)D * D * 2);
  u16* wtW1 = (u16*)alloc((size_t)D * FF * 2);
  u16* wtW2 = (u16*)alloc((size_t)D * FF * 2);
  char* uni = (char*)alloc((size_t)Mw * FF * 2);  // QKV(36MB)+Vt(8MB) | hb(48MB)
  u16* QKV = (u16*)uni;
  u16* Vt = (u16*)(uni + ((size_t)40 << 20));
  u16* hb = (u16*)uni;
  u16* AOb = (u16*)alloc((size_t)Mw * D * 2);
  u16* tmpb = (u16*)alloc((size_t)2 * Mw * D * 2);  // 2 split-K bf16 partials
  int* t2w = (int*)alloc((size_t)Mc * 4);
  int* t2s = (int*)alloc((size_t)Mc * 4);
  int* wlen = (int*)alloc((size_t)NW * 4);
  (void)ws_size; (void)in_sizes; (void)n_in;

  posadd<<<Mc, 256, 0, stream>>>(encoded, pos, xb_ctx);

  auto transpose_layer = [&](int p, int l) {
    const size_t oDD = (size_t)l * D * D, oDF = (size_t)l * D * FF;
    TBatch tb;
    tb.src[0] = W[p][0] + oDD; tb.dst[0] = wtQKV;                 tb.Kd[0] = D;  tb.Nd[0] = D;
    tb.src[1] = W[p][1] + oDD; tb.dst[1] = wtQKV + (size_t)D * D; tb.Kd[1] = D;  tb.Nd[1] = D;
    tb.src[2] = W[p][2] + oDD; tb.dst[2] = wtQKV + (size_t)2 * D * D; tb.Kd[2] = D; tb.Nd[2] = D;
    tb.src[3] = W[p][3] + oDD; tb.dst[3] = wtO;                   tb.Kd[3] = D;  tb.Nd[3] = D;
    tb.src[4] = W[p][11] + oDF; tb.dst[4] = wtW1;                 tb.Kd[4] = D;  tb.Nd[4] = FF;
    tb.src[5] = W[p][13] + oDF; tb.dst[5] = wtW2;                 tb.Kd[5] = FF; tb.Nd[5] = D;
    int base = 0;
    for (int i = 0; i < 6; i++) {
      tb.base[i] = base;
      base += (tb.Kd[i] / 64) * (tb.Nd[i] / 64);
    }
    transpose_batch<<<base, 256, 0, stream>>>(tb, 0);
  };

  // full-width layer: QKV -> attn -> O(splitK2) -> LN -> FFN1 -> FFN2(splitK2) -> LN
  auto full_layer = [&](int p, int l, u16* xb, int M, bool is_ctx) {
    transpose_layer(p, l);
    gemm_bt<1, true, false><<<(3 * D / 256) * (M / 128), 256, 0, stream>>>(
        xb, wtQKV, W[p][4] + (size_t)l * D, W[p][5] + (size_t)l * D,
        W[p][6] + (size_t)l * D, QKV, M, 3 * D, D, D, D, 3 * D / 256);
    if (is_ctx) {
      transpose_v<<<dim3(4, H, B), 256, 0, stream>>>(QKV, Vt);
      attn_ctx<<<dim3(4, H, B), 256, 0, stream>>>(QKV, Vt, AOb, lengths);
    } else {
      attn_word<<<(NW * H * MAXL + 255) / 256, 256, 0, stream>>>(QKV, wlen, AOb, NW);
    }
    gemm_bt<3, false, true><<<2 * (D / 256) * (M / 128), 256, 0, stream>>>(
        AOb, wtO, nullptr, nullptr, nullptr, tmpb, M, D, 512, D, D, D / 256);
    ln_resid2<1, false><<<M, 256, 0, stream>>>(xb, tmpb, tmpb + (size_t)M * D,
                                               W[p][7] + (size_t)l * D, W[p][14] + (size_t)l * D,
                                               W[p][9] + (size_t)l * D, xb, nullptr);
    gemm_bt<2, false, false><<<(FF / 256) * (M / 128), 256, 0, stream>>>(
        xb, wtW1, W[p][12] + (size_t)l * FF, nullptr, nullptr, hb, M, FF, D, D, D, FF / 256);
    gemm_bt<3, false, true><<<2 * (D / 256) * (M / 128), 256, 0, stream>>>(
        hb, wtW2, nullptr, nullptr, nullptr, tmpb, M, D, 2048, FF, FF, D / 256);
    ln_resid2<1, false><<<M, 256, 0, stream>>>(xb, tmpb, tmpb + (size_t)M * D,
                                               W[p][8] + (size_t)l * D, W[p][15] + (size_t)l * D,
                                               W[p][10] + (size_t)l * D, xb, nullptr);
  };

  // ctx encoder (both layers full)
  full_layer(0, 0, xb_ctx, Mc, true);
  full_layer(0, 1, xb_ctx, Mc, true);

  scan_words<<<1, 64, 0, stream>>>(labels, t2w, t2s, wlen);
  build_winp<<<Mw, 256, 0, stream>>>(pos, spec, wlen, xb_word);
  scatter_tokens<<<Mc, 256, 0, stream>>>(xb_ctx, t2w, t2s, xb_word);

  // word layer 0: full
  full_layer(1, 0, xb_word, Mw, false);

  // word layer 1: only BOS rows (sl==0) survive to the output -> compact M=NW tail
  {
    const int p = 1, l = 1;
    transpose_layer(p, l);
    // QKV full (K/V needed for all slots)
    gemm_bt<1, true, false><<<(3 * D / 256) * (Mw / 128), 256, 0, stream>>>(
        xb_word, wtQKV, W[p][4] + (size_t)l * D, W[p][5] + (size_t)l * D,
        W[p][6] + (size_t)l * D, QKV, Mw, 3 * D, D, D, D, 3 * D / 256);
    // attention: BOS queries only -> compact AO [NW][1024]
    attn_word_bos<<<(NW * H + 255) / 256, 256, 0, stream>>>(QKV, wlen, AOb, NW);
    // O projection compact: M=NW
    gemm_bt<3, false, true><<<2 * (D / 256) * (NW / 128), 256, 0, stream>>>(
        AOb, wtO, nullptr, nullptr, nullptr, tmpb, NW, D, 512, D, D, D / 256);
    // LN: residual = xb_word rows at stride MAXL (slot 0), output compact xc
    ln_resid2<MAXL, false><<<NW, 256, 0, stream>>>(
        xb_word, tmpb, tmpb + (size_t)NW * D, W[p][7] + (size_t)l * D,
        W[p][14] + (size_t)l * D, W[p][9] + (size_t)l * D, xc, nullptr);
    // FFN1 compact
    gemm_bt<2, false, false><<<(FF / 256) * (NW / 128), 256, 0, stream>>>(
        xc, wtW1, W[p][12] + (size_t)l * FF, nullptr, nullptr, hb, NW, FF, D, D, D, FF / 256);
    // FFN2 compact splitK2
    gemm_bt<3, false, true><<<2 * (D / 256) * (NW / 128), 256, 0, stream>>>(
        hb, wtW2, nullptr, nullptr, nullptr, tmpb, NW, D, 2048, FF, FF, D / 256);
    // final LN: residual = xc (compact), write f32 directly to d_out
    ln_resid2<1, true><<<NW, 256, 0, stream>>>(
        xc, tmpb, tmpb + (size_t)NW * D, W[p][8] + (size_t)l * D,
        W[p][15] + (size_t)l * D, W[p][10] + (size_t)l * D, xc, (float*)d_out);
  }
}

// Round 16
// 911.776 us; speedup vs baseline: 5.5030x; 1.0015x over previous
//
#include <hip/hip_runtime.h>
#include <stdint.h>

typedef unsigned short u16;
typedef __attribute__((ext_vector_type(8))) short short8;
typedef __attribute__((ext_vector_type(4))) short short4v;
typedef __attribute__((ext_vector_type(4))) float f32x4;

#define DEV static __device__ __forceinline__

constexpr int B = 16, S = 256, D = 1024, H = 16, LYR = 2, FF = 4096;
constexpr int Mc = B * S;
constexpr int MAXL = 6;
constexpr int QKVS = 3 * D;

DEV u16 f2b(float f) {
  union { float f; uint32_t u; } a; a.f = f;
  uint32_t r = a.u + 0x7fffu + ((a.u >> 16) & 1u);
  return (u16)(r >> 16);
}
DEV float b2f(u16 b) {
  union { uint32_t u; float f; } a; a.u = ((uint32_t)b) << 16;
  return a.f;
}

DEV void glds16(const u16* g, u16* l) {
  __builtin_amdgcn_global_load_lds((const __attribute__((address_space(1))) void*)g,
                                   (__attribute__((address_space(3))) void*)l, 16, 0, 0);
}

// ---------------- batched weight transpose: 6 x (W[K][N] f32 -> Wt[N][K] bf16) ----------------
struct TBatch {
  const float* src[6];
  u16* dst[6];
  int Kd[6];
  int Nd[6];
  int base[6];
};

__global__ __launch_bounds__(256) void transpose_batch(TBatch tb, int unused) {
  __shared__ float tile[64][65];
  const int bid = blockIdx.x;
  int wi = 0;
#pragma unroll
  for (int i = 1; i < 6; i++)
    if (bid >= tb.base[i]) wi = i;
  const float* __restrict__ W = tb.src[wi];
  u16* __restrict__ Wt = tb.dst[wi];
  const int K = tb.Kd[wi], N = tb.Nd[wi];
  const int local = bid - tb.base[wi];
  const int ntx = N >> 6;
  const int bn = (local % ntx) * 64, bk = (local / ntx) * 64;
  const int t = threadIdx.x;
  const int lr = t >> 2, lc = (t & 3) * 16;
#pragma unroll
  for (int q = 0; q < 4; q++) {
    float4 v = *(const float4*)&W[(size_t)(bk + lr) * N + bn + lc + q * 4];
    *(float4*)&tile[lr][lc + q * 4] = v;
  }
  __syncthreads();
  const int k0 = (t & 7) * 8;
#pragma unroll
  for (int p = 0; p < 2; p++) {
    const int n = (t >> 3) + p * 32;
    short8 o;
#pragma unroll
    for (int j = 0; j < 8; j++) o[j] = (short)f2b(tile[k0 + j][n]);
    *(short8*)&Wt[(size_t)(bn + n) * K + bk + k0] = o;
  }
}

// ---- bf16 MFMA GEMM (proven optimum): 128x256, 4 waves, BK=64, single-buffer 2-phase,
// T2 both-sides chunk swizzle, T1 XCD chunked swizzle. Separate A/B row strides + ldc ----
// EPI: 1 = bf16+bias (SPLITB selects per-1024-col group), 2 = relu->bf16+bias,
//      3 = bf16 partial (no bias).  SPLITK: grid doubled, upper half at K-offset K.

template <int PASSES>
DEV void stage_rows(const u16* P, int lda, int k0, u16* Dst, int t) {
#pragma unroll
  for (int p = 0; p < PASSES; p++)
    glds16(P + (size_t)(p * 32) * lda + k0, Dst + p * 2048 + t * 8);
}

DEV void compute_tile(const u16* Asb, const u16* Bsb, f32x4 (&acc)[4][8],
                      int wm, int wn, int li, int hi) {
#pragma unroll
  for (int ks = 0; ks < 2; ks++) {
    const int ch = ((((ks << 2) | hi) ^ (li & 7)) * 8);
    short8 af[4], bfr[8];
#pragma unroll
    for (int i = 0; i < 4; i++)
      af[i] = *(const short8*)&Asb[(wm + i * 16 + li) * 64 + ch];
#pragma unroll
    for (int j = 0; j < 8; j++)
      bfr[j] = *(const short8*)&Bsb[(wn + j * 16 + li) * 64 + ch];
#pragma unroll
    for (int i = 0; i < 4; i++)
#pragma unroll
      for (int j = 0; j < 8; j++)
        acc[i][j] = __builtin_amdgcn_mfma_f32_16x16x32_bf16(af[i], bfr[j], acc[i][j], 0, 0, 0);
  }
}

template <int EPI, bool SPLITB, bool SPLITK>
__global__ __launch_bounds__(256, 2) void gemm_bt(const u16* __restrict__ A,
                                                  const u16* __restrict__ Bt,
                                                  const float* __restrict__ bias0,
                                                  const float* __restrict__ bias1,
                                                  const float* __restrict__ bias2,
                                                  u16* __restrict__ Cb,
                                                  int M, int N, int K, int ldaA, int ldaB,
                                                  int ldc, int NB) {
  __shared__ u16 As[128 * 64];
  __shared__ u16 Bs[256 * 64];
  const int t = threadIdx.x, lane = t & 63, w = t >> 6;
  const int wm = (w >> 1) * 64, wn = (w & 1) * 128;
  const int nwg = gridDim.x;
  const int cpx = nwg >> 3;
  const int swz = (blockIdx.x & 7) * cpx + (blockIdx.x >> 3);
  int sblk = 0, rem = swz;
  if (SPLITK) {
    const int tps = nwg >> 1;
    sblk = (swz >= tps) ? 1 : 0;
    rem = swz - sblk * tps;
  }
  const int n0 = (rem % NB) * 256, m0 = (rem / NB) * 128;
  const int pr = t >> 3;
  const int scb = (((t & 7) ^ (pr & 7)) * 8);
  f32x4 acc[4][8] = {};
  const u16* Ap = A + (size_t)sblk * K + (size_t)(m0 + pr) * ldaA + scb;
  const u16* Bp = Bt + (size_t)sblk * K + (size_t)(n0 + pr) * ldaB + scb;
  const int li = lane & 15, hi = lane >> 4;

  for (int k0 = 0; k0 < K; k0 += 64) {
    stage_rows<4>(Ap, ldaA, k0, &As[0], t);
    stage_rows<8>(Bp, ldaB, k0, &Bs[0], t);
    __syncthreads();  // drains vmcnt; staged tile visible
    compute_tile(&As[0], &Bs[0], acc, wm, wn, li, hi);
    __syncthreads();  // all waves done reading before next overwrite
  }

  u16* Cbs = Cb;
  if (SPLITK && EPI == 3) Cbs = Cb + (size_t)sblk * M * N;
  const int rg = hi * 4;
#pragma unroll
  for (int j = 0; j < 8; j++) {
    const int col = n0 + wn + j * 16 + li;
    float bv = 0.f;
    if (EPI != 3)
      bv = SPLITB ? (col < 1024 ? bias0 : col < 2048 ? bias1 : bias2)[col & 1023]
                  : bias0[col];
#pragma unroll
    for (int i = 0; i < 4; i++) {
      const int row0 = m0 + wm + i * 16 + rg;
#pragma unroll
      for (int r = 0; r < 4; r++) {
        float v = acc[i][j][r] + bv;
        if (EPI == 2) v = fmaxf(v, 0.f);
        Cbs[(size_t)(row0 + r) * ldc + col] = f2b(v);
      }
    }
  }
}

// ---------------- per-head V transpose (from fused QKV) ----------------
__global__ __launch_bounds__(256) void transpose_v(const u16* __restrict__ QKV,
                                                   u16* __restrict__ Vt) {
  const int kb = blockIdx.x, h = blockIdx.y, b = blockIdx.z;
  __shared__ u16 tile[64][72];
  const int t = threadIdx.x, lr = t >> 3, lc = (t & 7) * 8;
#pragma unroll
  for (int p = 0; p < 2; p++) {
    int r = lr + p * 32;
    *(short8*)&tile[r][lc] =
        *(const short8*)&QKV[(size_t)(b * 256 + kb * 64 + r) * QKVS + 2048 + h * 64 + lc];
  }
  __syncthreads();
#pragma unroll
  for (int p = 0; p < 2; p++) {
    int hd = lr + p * 32;
    short8 v8;
#pragma unroll
    for (int j = 0; j < 8; j++) v8[j] = (short)tile[lc + j][hd];
    *(short8*)&Vt[(size_t)((b * 16 + h) * 64 + hd) * 256 + kb * 64 + lc] = v8;
  }
}

// ---------------- fused ctx attention ----------------
__global__ __launch_bounds__(256) void attn_ctx(const u16* __restrict__ QKV,
                                                const u16* __restrict__ Vt,
                                                u16* __restrict__ AO,
                                                const int* __restrict__ lengths) {
  const int qt = blockIdx.x, h = blockIdx.y, b = blockIdx.z;
  __shared__ u16 Qs[64 * 64], Ks[64 * 64], Vs[64 * 64], Ps[64 * 64];
  const int t = threadIdx.x, lane = t & 63, w = t >> 6;
  const int len = lengths[b];
  const bool full = (len >= 256);
  const int lr = t >> 3, lc = (t & 7) * 8;
#pragma unroll
  for (int p = 0; p < 2; p++) {
    int r = lr + p * 32;
    *(short8*)&Qs[r * 64 + lc] =
        *(const short8*)&QKV[(size_t)(b * 256 + qt * 64 + r) * QKVS + h * 64 + lc];
  }
  const int li = lane & 15, kk = (lane >> 4) * 8, rg = (lane >> 4) * 4;
  float mrun[4], lrun[4];
  f32x4 oacc[4] = {};
#pragma unroll
  for (int r = 0; r < 4; r++) { mrun[r] = -1e30f; lrun[r] = 0.f; }

  for (int kt = 0; kt < 4; kt++) {
    __syncthreads();
#pragma unroll
    for (int p = 0; p < 2; p++) {
      int r = lr + p * 32;
      *(short8*)&Ks[r * 64 + lc] =
          *(const short8*)&QKV[(size_t)(b * 256 + kt * 64 + r) * QKVS + 1024 + h * 64 + lc];
      *(short8*)&Vs[r * 64 + lc] =
          *(const short8*)&Vt[(size_t)((b * 16 + h) * 64 + r) * 256 + kt * 64 + lc];
    }
    __syncthreads();
    f32x4 s[4] = {};
    short8 aq0 = *(const short8*)&Qs[(w * 16 + li) * 64 + kk];
    short8 aq1 = *(const short8*)&Qs[(w * 16 + li) * 64 + 32 + kk];
    __builtin_amdgcn_s_setprio(1);
#pragma unroll
    for (int fn = 0; fn < 4; fn++) {
      short8 b0 = *(const short8*)&Ks[(fn * 16 + li) * 64 + kk];
      short8 b1 = *(const short8*)&Ks[(fn * 16 + li) * 64 + 32 + kk];
      s[fn] = __builtin_amdgcn_mfma_f32_16x16x32_bf16(aq0, b0, s[fn], 0, 0, 0);
      s[fn] = __builtin_amdgcn_mfma_f32_16x16x32_bf16(aq1, b1, s[fn], 0, 0, 0);
    }
    __builtin_amdgcn_s_setprio(0);
    float pv[4][4];
    if (full) {
#pragma unroll
      for (int r = 0; r < 4; r++) {
        float mx = -1e30f;
#pragma unroll
        for (int fn = 0; fn < 4; fn++) {
          float v = s[fn][r] * 0.125f;
          pv[fn][r] = v;
          mx = fmaxf(mx, v);
        }
#pragma unroll
        for (int d = 1; d < 16; d <<= 1) mx = fmaxf(mx, __shfl_xor(mx, d));
        if (mx > mrun[r] + 8.f) {
          float sf = __expf(mrun[r] - mx);
          mrun[r] = mx;
          lrun[r] *= sf;
#pragma unroll
          for (int fn = 0; fn < 4; fn++) oacc[fn][r] *= sf;
        }
        float rs = 0.f;
#pragma unroll
        for (int fn = 0; fn < 4; fn++) {
          float p = __expf(pv[fn][r] - mrun[r]);
          pv[fn][r] = p;
          rs += p;
        }
#pragma unroll
        for (int d = 1; d < 16; d <<= 1) rs += __shfl_xor(rs, d);
        lrun[r] += rs;
      }
    } else {
#pragma unroll
      for (int r = 0; r < 4; r++) {
        float mx = -1e30f;
#pragma unroll
        for (int fn = 0; fn < 4; fn++) {
          int key = kt * 64 + fn * 16 + li;
          float v = (key < len) ? s[fn][r] * 0.125f : -1e30f;
          pv[fn][r] = v;
          mx = fmaxf(mx, v);
        }
#pragma unroll
        for (int d = 1; d < 16; d <<= 1) mx = fmaxf(mx, __shfl_xor(mx, d));
        float mnew = fmaxf(mrun[r], mx);
        float sf = __expf(mrun[r] - mnew);
        mrun[r] = mnew;
        float rs = 0.f;
#pragma unroll
        for (int fn = 0; fn < 4; fn++) {
          int key = kt * 64 + fn * 16 + li;
          float p = (key < len) ? __expf(pv[fn][r] - mnew) : 0.f;
          pv[fn][r] = p;
          rs += p;
        }
#pragma unroll
        for (int d = 1; d < 16; d <<= 1) rs += __shfl_xor(rs, d);
        lrun[r] = lrun[r] * sf + rs;
#pragma unroll
        for (int fn = 0; fn < 4; fn++) oacc[fn][r] *= sf;
      }
    }
#pragma unroll
    for (int fn = 0; fn < 4; fn++)
#pragma unroll
      for (int r = 0; r < 4; r++)
        Ps[(w * 16 + rg + r) * 64 + fn * 16 + li] = f2b(pv[fn][r]);
    __builtin_amdgcn_s_setprio(1);
#pragma unroll
    for (int ks = 0; ks < 2; ks++) {
      short8 ap = *(const short8*)&Ps[(w * 16 + li) * 64 + ks * 32 + kk];
#pragma unroll
      for (int fn = 0; fn < 4; fn++) {
        short8 bv = *(const short8*)&Vs[(fn * 16 + li) * 64 + ks * 32 + kk];
        oacc[fn] = __builtin_amdgcn_mfma_f32_16x16x32_bf16(ap, bv, oacc[fn], 0, 0, 0);
      }
    }
    __builtin_amdgcn_s_setprio(0);
  }
#pragma unroll
  for (int r = 0; r < 4; r++) {
    float inv = 1.f / fmaxf(lrun[r], 1e-30f);
    int row = b * 256 + qt * 64 + w * 16 + rg + r;
#pragma unroll
    for (int fn = 0; fn < 4; fn++) {
      int col = h * 64 + fn * 16 + li;
      AO[(size_t)row * 1024 + col] = f2b(oacc[fn][r] * inv);
    }
  }
}

// ---------------- word attention (full rows; used for word layer 0) ----------------
__global__ __launch_bounds__(256) void attn_word(const u16* __restrict__ QKV,
                                                 const int* __restrict__ wlen,
                                                 u16* __restrict__ AO, int NW) {
  const int idx = blockIdx.x * 256 + threadIdx.x;
  if (idx >= NW * 16 * MAXL) return;
  const int i = idx % MAXL, h = (idx / MAXL) % 16, wd = idx / (MAXL * 16);
  const int len = wlen[wd];
  const size_t rowb = (size_t)(wd * MAXL + i) * QKVS;
  float q[64];
#pragma unroll
  for (int d = 0; d < 64; d += 8) {
    short8 q8 = *(const short8*)&QKV[rowb + h * 64 + d];
#pragma unroll
    for (int e = 0; e < 8; e++) q[d + e] = b2f((u16)q8[e]);
  }
  float sc[MAXL];
  float mx = -1e30f;
  for (int j = 0; j < MAXL; j++) {
    if (j >= len) { sc[j] = -1e30f; continue; }
    const size_t koff = (size_t)(wd * MAXL + j) * QKVS + 1024 + h * 64;
    float dot = 0.f;
#pragma unroll
    for (int d = 0; d < 64; d += 8) {
      short8 k8 = *(const short8*)&QKV[koff + d];
#pragma unroll
      for (int e = 0; e < 8; e++) dot += q[d + e] * b2f((u16)k8[e]);
    }
    sc[j] = dot * 0.125f;
    mx = fmaxf(mx, sc[j]);
  }
  float p[MAXL], l = 0.f;
  for (int j = 0; j < MAXL; j++) {
    p[j] = (j < len) ? __expf(sc[j] - mx) : 0.f;
    l += p[j];
  }
  const float rl = 1.f / fmaxf(l, 1e-30f);
  for (int j = 0; j < MAXL; j++) p[j] *= rl;
#pragma unroll
  for (int d = 0; d < 64; d += 8) {
    float acc[8] = {};
    for (int j = 0; j < MAXL; j++) {
      if (j >= len) break;
      short8 v8 = *(const short8*)&QKV[(size_t)(wd * MAXL + j) * QKVS + 2048 + h * 64 + d];
#pragma unroll
      for (int e = 0; e < 8; e++) acc[e] += p[j] * b2f((u16)v8[e]);
    }
    short8 o8;
#pragma unroll
    for (int e = 0; e < 8; e++) o8[e] = (short)f2b(acc[e]);
    *(short8*)&AO[(size_t)(wd * MAXL + i) * 1024 + h * 64 + d] = o8;
  }
}

// ---- word attention, BOS queries only (word layer 2): Q from compact Qc [NW][1024] ----
__global__ __launch_bounds__(256) void attn_word_bos(const u16* __restrict__ Qc,
                                                     const u16* __restrict__ QKV,
                                                     const int* __restrict__ wlen,
                                                     u16* __restrict__ AOc, int NW) {
  const int idx = blockIdx.x * 256 + threadIdx.x;
  if (idx >= NW * 16) return;
  const int h = idx % 16, wd = idx / 16;
  const int len = wlen[wd];
  float q[64];
#pragma unroll
  for (int d = 0; d < 64; d += 8) {
    short8 q8 = *(const short8*)&Qc[(size_t)wd * 1024 + h * 64 + d];
#pragma unroll
    for (int e = 0; e < 8; e++) q[d + e] = b2f((u16)q8[e]);
  }
  float sc[MAXL];
  float mx = -1e30f;
  for (int j = 0; j < MAXL; j++) {
    if (j >= len) { sc[j] = -1e30f; continue; }
    const size_t koff = (size_t)(wd * MAXL + j) * QKVS + 1024 + h * 64;
    float dot = 0.f;
#pragma unroll
    for (int d = 0; d < 64; d += 8) {
      short8 k8 = *(const short8*)&QKV[koff + d];
#pragma unroll
      for (int e = 0; e < 8; e++) dot += q[d + e] * b2f((u16)k8[e]);
    }
    sc[j] = dot * 0.125f;
    mx = fmaxf(mx, sc[j]);
  }
  float p[MAXL], l = 0.f;
  for (int j = 0; j < MAXL; j++) {
    p[j] = (j < len) ? __expf(sc[j] - mx) : 0.f;
    l += p[j];
  }
  const float rl = 1.f / fmaxf(l, 1e-30f);
  for (int j = 0; j < MAXL; j++) p[j] *= rl;
#pragma unroll
  for (int d = 0; d < 64; d += 8) {
    float acc[8] = {};
    for (int j = 0; j < MAXL; j++) {
      if (j >= len) break;
      short8 v8 = *(const short8*)&QKV[(size_t)(wd * MAXL + j) * QKVS + 2048 + h * 64 + d];
#pragma unroll
      for (int e = 0; e < 8; e++) acc[e] += p[j] * b2f((u16)v8[e]);
    }
    short8 o8;
#pragma unroll
    for (int e = 0; e < 8; e++) o8[e] = (short)f2b(acc[e]);
    *(short8*)&AOc[(size_t)wd * 1024 + h * 64 + d] = o8;
  }
}

// ---- residual (bf16, row-stride RS) + 2 split-K bf16 partials + bias + LayerNorm ----
template <int RS, bool WF32>
__global__ __launch_bounds__(256) void ln_resid2(const u16* __restrict__ Xin,
                                                 const u16* __restrict__ P0,
                                                 const u16* __restrict__ P1,
                                                 const float* __restrict__ bias,
                                                 const float* __restrict__ g,
                                                 const float* __restrict__ be,
                                                 u16* __restrict__ Xbo,
                                                 float* __restrict__ Xo) {
  const int row = blockIdx.x, t = threadIdx.x;
  const size_t base = (size_t)row * 1024 + t * 4;
  const size_t basein = (size_t)row * RS * 1024 + t * 4;
  short4v x4 = *(const short4v*)&Xin[basein];
  short4v p0 = *(const short4v*)&P0[base];
  short4v p1 = *(const short4v*)&P1[base];
  float4 bb = *(const float4*)&bias[t * 4];
  float v[4];
  v[0] = b2f((u16)x4[0]) + b2f((u16)p0[0]) + b2f((u16)p1[0]) + bb.x;
  v[1] = b2f((u16)x4[1]) + b2f((u16)p0[1]) + b2f((u16)p1[1]) + bb.y;
  v[2] = b2f((u16)x4[2]) + b2f((u16)p0[2]) + b2f((u16)p1[2]) + bb.z;
  v[3] = b2f((u16)x4[3]) + b2f((u16)p0[3]) + b2f((u16)p1[3]) + bb.w;
  float s = v[0] + v[1] + v[2] + v[3];
  float q = v[0] * v[0] + v[1] * v[1] + v[2] * v[2] + v[3] * v[3];
#pragma unroll
  for (int d = 1; d < 64; d <<= 1) { s += __shfl_xor(s, d); q += __shfl_xor(q, d); }
  __shared__ float ss[4], qq[4];
  if ((t & 63) == 0) { ss[t >> 6] = s; qq[t >> 6] = q; }
  __syncthreads();
  s = ss[0] + ss[1] + ss[2] + ss[3];
  q = qq[0] + qq[1] + qq[2] + qq[3];
  const float mean = s * (1.f / 1024.f);
  const float var = q * (1.f / 1024.f) - mean * mean;
  const float rstd = rsqrtf(var + 1e-5f);
  float4 gv = *(const float4*)&g[t * 4];
  float4 bv = *(const float4*)&be[t * 4];
  float y[4];
  y[0] = (v[0] - mean) * rstd * gv.x + bv.x;
  y[1] = (v[1] - mean) * rstd * gv.y + bv.y;
  y[2] = (v[2] - mean) * rstd * gv.z + bv.z;
  y[3] = (v[3] - mean) * rstd * gv.w + bv.w;
  if (WF32) *(float4*)&Xo[base] = make_float4(y[0], y[1], y[2], y[3]);
  short4v o = { (short)f2b(y[0]), (short)f2b(y[1]), (short)f2b(y[2]), (short)f2b(y[3]) };
  *(short4v*)&Xbo[base] = o;
}

// ---------------- misc small kernels (bf16 residual stream) ----------------
__global__ __launch_bounds__(256) void posadd(const float* __restrict__ enc,
                                              const float* __restrict__ pos,
                                              u16* __restrict__ Xb) {
  const int row = blockIdx.x, t = threadIdx.x;
  const int sp = row & 255;
  const size_t base = (size_t)row * 1024 + t * 4;
  float4 e = *(const float4*)&enc[base];
  float4 p = *(const float4*)&pos[(size_t)sp * 1024 + t * 4];
  short4v o = { (short)f2b(e.x + p.x), (short)f2b(e.y + p.y),
                (short)f2b(e.z + p.z), (short)f2b(e.w + p.w) };
  *(short4v*)&Xb[base] = o;
}

__global__ void scan_words(const int* __restrict__ labels, int* __restrict__ t2w,
                           int* __restrict__ t2s, int* __restrict__ wlen) {
  __shared__ int rowEnds[16], rowBase[16];
  const int t = threadIdx.x;
  if (t < 16) {
    int c = 0;
    for (int s = 0; s < 256; s++) c += (labels[t * 256 + s] == 2);
    rowEnds[t] = c;
  }
  __syncthreads();
  if (t == 0) {
    int acc = 0;
    for (int b2 = 0; b2 < 16; b2++) { rowBase[b2] = acc; acc += rowEnds[b2]; }
  }
  __syncthreads();
  if (t < 16) {
    int wc = rowBase[t], fr = 0;
    for (int s = 0; s < 256; s++) {
      const int tok = t * 256 + s, lb = labels[tok];
      if (lb == 1) { fr++; t2w[tok] = wc; t2s[tok] = fr; }
      else if (lb == 2) { t2w[tok] = wc; t2s[tok] = fr + 1; wlen[wc] = fr + 3; wc++; fr = 0; }
      else { t2w[tok] = -1; t2s[tok] = 0; fr = 0; }
    }
  }
}

__global__ __launch_bounds__(256) void build_winp(const float* __restrict__ pos,
                                                  const float* __restrict__ spec,
                                                  const int* __restrict__ wlen,
                                                  u16* __restrict__ Xb) {
  const int row = blockIdx.x;
  const int wd = row / MAXL, sl = row % MAXL;
  const int len = wlen[wd];
  const int t = threadIdx.x;
  const size_t cb = t * 4;
  float4 p = *(const float4*)&pos[(size_t)sl * 1024 + cb];
  float4 e = make_float4(0.f, 0.f, 0.f, 0.f);
  if (sl == 0) e = *(const float4*)&spec[cb];
  else if (sl == len - 1) e = *(const float4*)&spec[1024 + cb];
  short4v o = { (short)f2b(p.x + e.x), (short)f2b(p.y + e.y),
                (short)f2b(p.z + e.z), (short)f2b(p.w + e.w) };
  *(short4v*)&Xb[(size_t)row * 1024 + cb] = o;
}

__global__ __launch_bounds__(256) void scatter_tokens(const u16* __restrict__ XcB,
                                                      const int* __restrict__ t2w,
                                                      const int* __restrict__ t2s,
                                                      u16* __restrict__ XW) {
  const int tok = blockIdx.x;
  const int wd = t2w[tok];
  if (wd < 0) return;
  const int row = wd * MAXL + t2s[tok];
  const size_t cb = threadIdx.x * 4;
  short4v a = *(const short4v*)&XcB[(size_t)tok * 1024 + cb];
  u16* dst = &XW[(size_t)row * 1024 + cb];
  short4v b2 = *(const short4v*)dst;
  short4v o;
#pragma unroll
  for (int e = 0; e < 4; e++) o[e] = (short)f2b(b2f((u16)a[e]) + b2f((u16)b2[e]));
  *(short4v*)dst = o;
}

// ---------------- host side ----------------
extern "C" void kernel_launch(void* const* d_in, const int* in_sizes, int n_in,
                              void* d_out, int out_size, void* d_ws, size_t ws_size,
                              hipStream_t stream) {
  const float* encoded = (const float*)d_in[0];
  const int* lengths = (const int*)d_in[1];
  const int* labels = (const int*)d_in[2];
  const float* pos = (const float*)d_in[4];
  const float* spec = (const float*)d_in[5];
  const float* W[2][16];
  for (int p = 0; p < 2; p++)
    for (int i = 0; i < 16; i++) W[p][i] = (const float*)d_in[6 + p * 16 + i];

  const int NW = out_size / D;  // 1024 words
  const int Mw = NW * MAXL;     // 6144 word-slot rows

  char* wp = (char*)d_ws;
  size_t off = 0;
  auto alloc = [&](size_t bytes) {
    void* r = wp + off;
    off += (bytes + 255) & ~(size_t)255;
    return r;
  };
  u16* xb_ctx = (u16*)alloc((size_t)Mc * D * 2);
  u16* xb_word = (u16*)alloc((size_t)Mw * D * 2);
  u16* xc = (u16*)alloc((size_t)NW * D * 2);   // compact word-l2 activations
  u16* Qc = (u16*)alloc((size_t)NW * D * 2);   // compact BOS queries
  u16* wtQKV = (u16*)alloc((size_t)3 * D * D * 2);
  u16* wtO = (u16*)alloc((size_t)D * D * 2);
  u16* wtW1 = (u16*)alloc((size_t)D * FF * 2);
  u16* wtW2 = (u16*)alloc((size_t)D * FF * 2);
  char* uni = (char*)alloc((size_t)Mw * FF * 2);  // QKV(36MB)+Vt(8MB) | hb(48MB)
  u16* QKV = (u16*)uni;
  u16* Vt = (u16*)(uni + ((size_t)40 << 20));
  u16* hb = (u16*)uni;
  u16* AOb = (u16*)alloc((size_t)Mw * D * 2);
  u16* tmpb = (u16*)alloc((size_t)2 * Mw * D * 2);  // 2 split-K bf16 partials
  int* t2w = (int*)alloc((size_t)Mc * 4);
  int* t2s = (int*)alloc((size_t)Mc * 4);
  int* wlen = (int*)alloc((size_t)NW * 4);
  (void)ws_size; (void)in_sizes; (void)n_in;

  posadd<<<Mc, 256, 0, stream>>>(encoded, pos, xb_ctx);

  auto transpose_layer = [&](int p, int l) {
    const size_t oDD = (size_t)l * D * D, oDF = (size_t)l * D * FF;
    TBatch tb;
    tb.src[0] = W[p][0] + oDD; tb.dst[0] = wtQKV;                 tb.Kd[0] = D;  tb.Nd[0] = D;
    tb.src[1] = W[p][1] + oDD; tb.dst[1] = wtQKV + (size_t)D * D; tb.Kd[1] = D;  tb.Nd[1] = D;
    tb.src[2] = W[p][2] + oDD; tb.dst[2] = wtQKV + (size_t)2 * D * D; tb.Kd[2] = D; tb.Nd[2] = D;
    tb.src[3] = W[p][3] + oDD; tb.dst[3] = wtO;                   tb.Kd[3] = D;  tb.Nd[3] = D;
    tb.src[4] = W[p][11] + oDF; tb.dst[4] = wtW1;                 tb.Kd[4] = D;  tb.Nd[4] = FF;
    tb.src[5] = W[p][13] + oDF; tb.dst[5] = wtW2;                 tb.Kd[5] = FF; tb.Nd[5] = D;
    int base = 0;
    for (int i = 0; i < 6; i++) {
      tb.base[i] = base;
      base += (tb.Kd[i] / 64) * (tb.Nd[i] / 64);
    }
    transpose_batch<<<base, 256, 0, stream>>>(tb, 0);
  };

  // full-width layer: QKV -> attn -> O(splitK2) -> LN -> FFN1 -> FFN2(splitK2) -> LN
  auto full_layer = [&](int p, int l, u16* xb, int M, bool is_ctx) {
    transpose_layer(p, l);
    gemm_bt<1, true, false><<<(3 * D / 256) * (M / 128), 256, 0, stream>>>(
        xb, wtQKV, W[p][4] + (size_t)l * D, W[p][5] + (size_t)l * D,
        W[p][6] + (size_t)l * D, QKV, M, 3 * D, D, D, D, 3 * D, 3 * D / 256);
    if (is_ctx) {
      transpose_v<<<dim3(4, H, B), 256, 0, stream>>>(QKV, Vt);
      attn_ctx<<<dim3(4, H, B), 256, 0, stream>>>(QKV, Vt, AOb, lengths);
    } else {
      attn_word<<<(NW * H * MAXL + 255) / 256, 256, 0, stream>>>(QKV, wlen, AOb, NW);
    }
    gemm_bt<3, false, true><<<2 * (D / 256) * (M / 128), 256, 0, stream>>>(
        AOb, wtO, nullptr, nullptr, nullptr, tmpb, M, D, 512, D, D, D, D / 256);
    ln_resid2<1, false><<<M, 256, 0, stream>>>(xb, tmpb, tmpb + (size_t)M * D,
                                               W[p][7] + (size_t)l * D, W[p][14] + (size_t)l * D,
                                               W[p][9] + (size_t)l * D, xb, nullptr);
    gemm_bt<2, false, false><<<(FF / 256) * (M / 128), 256, 0, stream>>>(
        xb, wtW1, W[p][12] + (size_t)l * FF, nullptr, nullptr, hb, M, FF, D, D, D, FF,
        FF / 256);
    gemm_bt<3, false, true><<<2 * (D / 256) * (M / 128), 256, 0, stream>>>(
        hb, wtW2, nullptr, nullptr, nullptr, tmpb, M, D, 2048, FF, FF, D, D / 256);
    ln_resid2<1, false><<<M, 256, 0, stream>>>(xb, tmpb, tmpb + (size_t)M * D,
                                               W[p][8] + (size_t)l * D, W[p][15] + (size_t)l * D,
                                               W[p][10] + (size_t)l * D, xb, nullptr);
  };

  // ctx encoder (both layers full)
  full_layer(0, 0, xb_ctx, Mc, true);
  full_layer(0, 1, xb_ctx, Mc, true);

  scan_words<<<1, 64, 0, stream>>>(labels, t2w, t2s, wlen);
  build_winp<<<Mw, 256, 0, stream>>>(pos, spec, wlen, xb_word);
  scatter_tokens<<<Mc, 256, 0, stream>>>(xb_ctx, t2w, t2s, xb_word);

  // word layer 0: full
  full_layer(1, 0, xb_word, Mw, false);

  // word layer 1: only BOS rows (sl==0) survive -> KV full + Q compact, compact tail
  {
    const int p = 1, l = 1;
    transpose_layer(p, l);
    // KV projection: full M, N=2048 (WK|WV), written strided into QKV cols 1024..3071
    gemm_bt<1, true, false><<<(2 * D / 256) * (Mw / 128), 256, 0, stream>>>(
        xb_word, wtQKV + (size_t)D * D, W[p][5] + (size_t)l * D, W[p][6] + (size_t)l * D,
        nullptr, QKV + 1024, Mw, 2 * D, D, D, D, 3 * D, 2 * D / 256);
    // Q projection: compact M=NW (BOS rows of xb_word via strided A), output Qc
    gemm_bt<1, false, false><<<(D / 256) * (NW / 128), 256, 0, stream>>>(
        xb_word, wtQKV, W[p][4] + (size_t)l * D, nullptr, nullptr, Qc, NW, D, D,
        MAXL * D, D, D, D / 256);
    // attention: BOS queries only -> compact AO [NW][1024]
    attn_word_bos<<<(NW * H + 255) / 256, 256, 0, stream>>>(Qc, QKV, wlen, AOb, NW);
    // O projection compact: M=NW, splitK2
    gemm_bt<3, false, true><<<2 * (D / 256) * (NW / 128), 256, 0, stream>>>(
        AOb, wtO, nullptr, nullptr, nullptr, tmpb, NW, D, 512, D, D, D, D / 256);
    // LN: residual = xb_word rows at stride MAXL (slot 0), output compact xc
    ln_resid2<MAXL, false><<<NW, 256, 0, stream>>>(
        xb_word, tmpb, tmpb + (size_t)NW * D, W[p][7] + (size_t)l * D,
        W[p][14] + (size_t)l * D, W[p][9] + (size_t)l * D, xc, nullptr);
    // FFN1 compact
    gemm_bt<2, false, false><<<(FF / 256) * (NW / 128), 256, 0, stream>>>(
        xc, wtW1, W[p][12] + (size_t)l * FF, nullptr, nullptr, hb, NW, FF, D, D, D, FF,
        FF / 256);
    // FFN2 compact splitK2
    gemm_bt<3, false, true><<<2 * (D / 256) * (NW / 128), 256, 0, stream>>>(
        hb, wtW2, nullptr, nullptr, nullptr, tmpb, NW, D, 2048, FF, FF, D, D / 256);
    // final LN: residual = xc (compact), write f32 directly to d_out
    ln_resid2<1, true><<<NW, 256, 0, stream>>>(
        xc, tmpb, tmpb + (size_t)NW * D, W[p][8] + (size_t)l * D,
        W[p][15] + (size_t)l * D, W[p][10] + (size_t)l * D, xc, (float*)d_out);
  }
}